// Round 7
// baseline (50257.431 us; speedup 1.0000x reference)
//
#include <hip/hip_runtime.h>
#include <math.h>

constexpr int NB    = 64;
constexpr int NT    = 256;
constexpr int NU    = 256;
constexpr int NMELc = 80;
constexpr int PREc  = 128;
constexpr int EMBc  = 15;
constexpr int NFc   = 128;
constexpr int ENCc  = 128;
constexpr int DECc  = 512;
constexpr int WMc   = 10;
constexpr int AKS   = 16;
constexpr int DBLK  = 512;   // decoder persistent grid (2 blocks/CU)
constexpr int EBLK  = 128;   // encoder persistent grid

__device__ __forceinline__ float sigm(float x) { return 1.0f / (1.0f + expf(-x)); }
__device__ __forceinline__ float softplusf(float x) { return fmaxf(x, 0.0f) + log1pf(expf(-fabsf(x))); }

// ---- relaxed agent-scope (cache-bypassing, fence-free) accessors ----
__device__ __forceinline__ float ldF(const float* p) {
  return __hip_atomic_load(p, __ATOMIC_RELAXED, __HIP_MEMORY_SCOPE_AGENT);
}
__device__ __forceinline__ void stF(float* p, float v) {
  __hip_atomic_store(p, v, __ATOMIC_RELAXED, __HIP_MEMORY_SCOPE_AGENT);
}
__device__ __forceinline__ float2 ldF2(const float* p) {
  unsigned long long u = __hip_atomic_load((const unsigned long long*)p, __ATOMIC_RELAXED,
                                           __HIP_MEMORY_SCOPE_AGENT);
  return __builtin_bit_cast(float2, u);
}
__device__ __forceinline__ void stF2(float* p, float2 v) {
  __hip_atomic_store((unsigned long long*)p, __builtin_bit_cast(unsigned long long, v),
                     __ATOMIC_RELAXED, __HIP_MEMORY_SCOPE_AGENT);
}
__device__ __forceinline__ void vdrain() { asm volatile("s_waitcnt vmcnt(0)" ::: "memory"); }

// ---- all-to-all flag barrier: 1 relaxed store per block, coalesced scan, NO RMW, NO fences ----
// flags[bid] monotonically increases (epoch). Data moved via bypass ops is visible at L3 once
// vmcnt drains (compiler emits full waitcnt before s_barrier), so no acquire/release needed.
__device__ __forceinline__ void gbarF(unsigned* flags, unsigned e, int nblk) {
  __syncthreads();
  vdrain();
  if (threadIdx.x == 0)
    __hip_atomic_store(&flags[blockIdx.x], e, __ATOMIC_RELAXED, __HIP_MEMORY_SCOPE_AGENT);
  bool ok;
  do {
    ok = true;
    for (int i = threadIdx.x; i < nblk; i += blockDim.x)
      ok &= (__hip_atomic_load(&flags[i], __ATOMIC_RELAXED, __HIP_MEMORY_SCOPE_AGENT) >= e);
  } while (!__syncthreads_and(ok));
}

// ---------------- generic dense ----------------
template <int K, int N, int RB>
__global__ void k_dense(const float* __restrict__ X, const float* __restrict__ W,
                        const float* __restrict__ bias, float* __restrict__ Y, int R) {
  __shared__ float xs[RB][K];
  int r0 = blockIdx.x * RB;
  int tid = threadIdx.x;  // 128
  for (int idx = tid; idx < RB * K; idx += 128) {
    int r = idx / K, k = idx % K;
    xs[r][k] = (r0 + r < R) ? X[(size_t)(r0 + r) * K + k] : 0.0f;
  }
  __syncthreads();
  int j = tid;
  if (j >= N) return;
  float acc[RB];
#pragma unroll
  for (int r = 0; r < RB; ++r) acc[r] = 0.f;
  for (int k = 0; k < K; ++k) {
    float w = W[(size_t)k * N + j];
#pragma unroll
    for (int r = 0; r < RB; ++r) acc[r] += xs[r][k] * w;
  }
  float bj = bias[j];
  for (int r = 0; r < RB; ++r)
    if (r0 + r < R) Y[(size_t)(r0 + r) * N + j] = acc[r] + bj;
}

// ---------------- embedding gather ----------------
__global__ void k_embed(const int* __restrict__ text, const float* __restrict__ emb,
                        float* __restrict__ out) {
  int idx = blockIdx.x * blockDim.x + threadIdx.x;
  if (idx >= NB * NU * EMBc) return;
  int c = idx % EMBc;
  int bu = idx / EMBc;
  int u = bu % NU, b = bu / NU;
  out[idx] = emb[text[u * NB + b] * EMBc + c];
}

// ---------------- merged conv weights ----------------
template <int CIN>
__global__ void k_weff(const float* __restrict__ w, const float* __restrict__ bb,
                       float* __restrict__ weff, float* __restrict__ beff) {
  int idx = blockIdx.x * blockDim.x + threadIdx.x;
  const int tot = 5 * CIN * NFc;
  if (idx < tot) {
    int f = idx % NFc;
    int tc = idx / NFc;
    int c = tc % CIN, t = tc / CIN;
    float m0 = (t == 2) ? 1.f : 0.f;
    float m1 = (t >= 1 && t <= 3) ? 1.f : 0.f;
    float w0 = w[((size_t)(0 * 5 + t) * CIN + c) * NFc + f];
    float w1 = w[((size_t)(1 * 5 + t) * CIN + c) * NFc + f];
    float w2 = w[((size_t)(2 * 5 + t) * CIN + c) * NFc + f];
    weff[idx] = w0 * m0 + w1 * m1 + w2;
  }
  if (idx < NFc) beff[idx] = bb[idx] + bb[NFc + idx] + bb[2 * NFc + idx];
}

// ---------------- conv stack ----------------
template <int CIN, bool RES>
__global__ void k_conv(const float* __restrict__ x, const float* __restrict__ weff,
                       const float* __restrict__ beff, float* __restrict__ y) {
  const int UT = 8;
  __shared__ float xs[(UT + 4) * CIN];
  int b = blockIdx.y, u0 = blockIdx.x * UT;
  int tid = threadIdx.x;  // 128
  for (int idx = tid; idx < (UT + 4) * CIN; idx += 128) {
    int c = idx % CIN;
    int uu = idx / CIN;
    int u = u0 + uu - 2;
    xs[idx] = (u >= 0 && u < NU) ? x[((size_t)b * NU + u) * CIN + c] : 0.f;
  }
  __syncthreads();
  int f = tid;
  float acc[UT];
#pragma unroll
  for (int r = 0; r < UT; ++r) acc[r] = beff[f];
  for (int t = 0; t < 5; ++t)
    for (int c = 0; c < CIN; ++c) {
      float w = weff[((size_t)t * CIN + c) * NFc + f];
#pragma unroll
      for (int r = 0; r < UT; ++r) acc[r] += xs[(r + t) * CIN + c] * w;
    }
  for (int r = 0; r < UT; ++r) {
    float v = fmaxf(acc[r], 0.f);
    if (RES) v += xs[(r + 2) * CIN + f];
    y[((size_t)b * NU + u0 + r) * NFc + f] = v;
  }
}

// ---------------- persistent encoder BiLSTM ----------------
struct EncP {
  const float *Wf, *bf, *Wb, *bb, *convt, *text_mask;
  float *ctx, *hbuf, *cbuf, *zE;
  unsigned* flags;
};
__global__ __launch_bounds__(128, 2) void k_encP(EncP P) {
  const size_t ZPS = (size_t)8 * NB * 512;
  __shared__ float hs[4][128];
  __shared__ float xs[4][64];
  int tid = threadIdx.x;
  int bid = blockIdx.x;
  int d = bid >> 6;
  int q = (bid >> 4) & 3;
  int g = bid & 15;
  int b0 = g * 4;
  const float* Wd = d ? P.Wb : P.Wf;
  const float* bd = d ? P.bb : P.bf;
  int j = tid;
  unsigned ep = 0;
  for (int u = 0; u <= NU; ++u) {
    if (u > 0) {
      int ig = u - 1;
      int upos = d ? (NU - 1 - ig) : ig;
      const float* zr = P.zE + (size_t)((u - 1) & 1) * ZPS + (size_t)d * 4 * NB * 512;
      for (int bi = 0; bi < 4; ++bi) {
        int b = b0 + bi;
        float zi = bd[j], zf = bd[128 + j], zg = bd[256 + j], zo = bd[384 + j];
        for (int qq = 0; qq < 4; ++qq) {
          const float* p = zr + ((size_t)qq * NB + b) * 512;
          zi += ldF(p + j);
          zf += ldF(p + 128 + j);
          zg += ldF(p + 256 + j);
          zo += ldF(p + 384 + j);
        }
        float cp = 0.f, hp = 0.f;
        if (u >= 2) {
          cp = ldF(P.cbuf + ((size_t)(d * 2 + (u & 1)) * NB + b) * 128 + j);
          hp = ldF(P.hbuf + ((size_t)(d * 2 + (u & 1)) * NB + b) * 128 + j);
        }
        float cn = sigm(zf) * cp + sigm(zi) * tanhf(zg);
        float hn = sigm(zo) * tanhf(cn);
        float mt = P.text_mask[upos * NB + b];
        hn = mt * hn + (1.f - mt) * hp;
        cn = mt * cn + (1.f - mt) * cp;
        hs[bi][j] = hn;
        if (q == 0) {
          stF(P.hbuf + ((size_t)(d * 2 + ((u - 1) & 1)) * NB + b) * 128 + j, hn);
          stF(P.cbuf + ((size_t)(d * 2 + ((u - 1) & 1)) * NB + b) * 128 + j, cn);
          P.ctx[((size_t)upos * NB + b) * 256 + d * 128 + j] = hn;  // consumed by next kernel
        }
      }
    } else {
#pragma unroll
      for (int bi = 0; bi < 4; ++bi) hs[bi][j] = 0.f;
    }
    if (u < NU) {
      __syncthreads();
      int k0 = q * 64;
      {
        int upos_x = d ? (NU - 1 - u) : u;
        for (int idx = tid; idx < 4 * 64; idx += 128) {
          int bi = idx >> 6, kk = idx & 63;
          int k = k0 + kk;
          float v = (k < 128) ? P.convt[((size_t)(b0 + bi) * NU + upos_x) * 128 + k]
                              : hs[bi][k - 128];
          xs[bi][kk] = v;
        }
      }
      __syncthreads();
      float4 acc[4];
#pragma unroll
      for (int bi = 0; bi < 4; ++bi) acc[bi] = make_float4(0.f, 0.f, 0.f, 0.f);
      const float4* Wp = (const float4*)Wd + (size_t)k0 * 128 + tid;
#pragma unroll 8
      for (int kk = 0; kk < 64; ++kk) {
        float4 w = Wp[(size_t)kk * 128];
#pragma unroll
        for (int bi = 0; bi < 4; ++bi) {
          float xv = xs[bi][kk];
          acc[bi].x += w.x * xv;
          acc[bi].y += w.y * xv;
          acc[bi].z += w.z * xv;
          acc[bi].w += w.w * xv;
        }
      }
      float* zwf = P.zE + (size_t)(u & 1) * ZPS + ((size_t)(d * 4 + q) * NB + b0) * 512 + tid * 4;
#pragma unroll
      for (int bi = 0; bi < 4; ++bi) {
        stF2(zwf + (size_t)bi * 512, make_float2(acc[bi].x, acc[bi].y));
        stF2(zwf + (size_t)bi * 512 + 2, make_float2(acc[bi].z, acc[bi].w));
      }
    }
    gbarF(P.flags, ++ep, EBLK);
  }
}

// ---------------- persistent decoder ----------------
// Chunks (16): c 0..5 -> z1 (K=1408: 5x240+208), c 6..9 -> za (K=896: 4x224),
//              c 10..15 -> z2 (5x240+208).
// X block decode: bg = bid>>7 (16 batches each), r = bid&127, c = r>>3, nc = r&7.
// Same (c,nc) blocks are 128 apart (same XCD): per-XCD weight slice ~3.75MB, L2-resident.
// X(t): z2(t), z1(t+1), za(t+2).  Y(t): gate2(t), gate1(t+1), att(t+2).
struct DecP {
  const float *corr, *mel_mask, *text_mask, *ctx;
  const float *w_att, *b_att, *w_rnn1, *b_rnn1, *w_rnn2, *b_rnn2, *w_proj, *b_proj;
  float *zX, *aw, *ak, *ah, *ac, *h1, *c1, *c2, *outs, *zerob;
  unsigned* flags;
};

__device__ __forceinline__ void do_gate(const float* zX, int clo, int chi, const float* bias,
                                        const float* cprev, const float* hprev, bool zfirst,
                                        const float* mm, float* hout, float* cout, int b, int j) {
  float2 zi = *(const float2*)(bias + j);
  float2 zf = *(const float2*)(bias + 512 + j);
  float2 zg = *(const float2*)(bias + 1024 + j);
  float2 zo = *(const float2*)(bias + 1536 + j);
  for (int c = clo; c <= chi; ++c) {
    const float* q = zX + ((size_t)c * NB + b) * 2048 + j;
    float2 a = ldF2(q), f2 = ldF2(q + 512), g2 = ldF2(q + 1024), o2 = ldF2(q + 1536);
    zi.x += a.x; zi.y += a.y;
    zf.x += f2.x; zf.y += f2.y;
    zg.x += g2.x; zg.y += g2.y;
    zo.x += o2.x; zo.y += o2.y;
  }
  float2 cp = zfirst ? make_float2(0.f, 0.f) : ldF2(cprev + (size_t)b * 512 + j);
  float2 hp = zfirst ? make_float2(0.f, 0.f) : ldF2(hprev + (size_t)b * 512 + j);
  float m = mm[b];
  float cnx = sigm(zf.x) * cp.x + sigm(zi.x) * tanhf(zg.x);
  float cny = sigm(zf.y) * cp.y + sigm(zi.y) * tanhf(zg.y);
  float hnx = sigm(zo.x) * tanhf(cnx);
  float hny = sigm(zo.y) * tanhf(cny);
  stF2(hout + (size_t)b * 512 + j, make_float2(m * hnx + (1.f - m) * hp.x,
                                               m * hny + (1.f - m) * hp.y));
  stF2(cout + (size_t)b * 512 + j, make_float2(m * cnx + (1.f - m) * cp.x,
                                               m * cny + (1.f - m) * cp.y));
}

__global__ __launch_bounds__(256, 2) void k_decP(DecP P) {
  __shared__ float xs[16][240];
  float* sh = &xs[0][0];
  int tid = threadIdx.x, bid = blockIdx.x;
  int bg = bid >> 7, r = bid & 127, c = r >> 3, nc = r & 7;
  int g, k0, klen;
  if (c < 6)       { g = 0; k0 = c * 240;        klen = (c == 5)  ? 208 : 240; }
  else if (c < 10) { g = 1; k0 = (c - 6) * 224;  klen = 224; }
  else             { g = 2; k0 = (c - 10) * 240; klen = (c == 15) ? 208 : 240; }
  const float* Wg = (g == 0) ? P.w_rnn1 : (g == 1 ? P.w_att : P.w_rnn2);
  const float4* W4 = (const float4*)Wg;
  int bsub = tid >> 6, ct = tid & 63;
  unsigned ep = 0;
  for (int t = -2; t < NT; ++t) {
    // ================= X phase =================
    int s = (g == 0) ? (t + 1) : (g == 1 ? (t + 2) : t);
    if (s >= 0 && s < NT) {
      const float* p0 = P.corr + (size_t)s * NB * PREc;
      const float *p1, *p2, *p3;
      int s1, s2_, s3;
      if (g == 1) {  // za(s): [corr_s, aw(s-1), ah(s-1)]
        bool z = (s == 0);
        int pp = (s - 1) & 1;
        p1 = z ? P.zerob : P.aw + (size_t)pp * NB * 256; s1 = z ? 0 : 256;
        p2 = z ? P.zerob : P.ah + (size_t)pp * NB * DECc; s2_ = z ? 0 : DECc;
        p3 = P.zerob; s3 = 0;
      } else if (g == 0) {  // z1(s): [corr_s, aw(s), ah(s), h1(s-1)]
        int pp = s & 1;
        p1 = P.aw + (size_t)pp * NB * 256; s1 = 256;
        p2 = P.ah + (size_t)pp * NB * DECc; s2_ = DECc;
        bool z = (s == 0);
        p3 = z ? P.zerob : P.h1 + (size_t)((s - 1) & 1) * NB * DECc; s3 = z ? 0 : DECc;
      } else {  // z2(s): [corr_s, aw(s), h1(s), h2(s-1)]
        int pp = s & 1;
        p1 = P.aw + (size_t)pp * NB * 256; s1 = 256;
        p2 = P.h1 + (size_t)pp * NB * DECc; s2_ = DECc;
        bool z = (s == 0);
        p3 = z ? P.zerob : P.outs + (size_t)(s - 1) * NB * DECc; s3 = z ? 0 : DECc;
      }
      // stage x: one row per pass, kk = tid -> global loads COALESCED, LDS writes conflict-free
      {
        int kk = tid;
        if (kk < klen) {
          int k = k0 + kk;
#pragma unroll 4
          for (int bi = 0; bi < 16; ++bi) {
            int b = bg * 16 + bi;
            float v;
            int kx = k;
            if (kx < PREc)
              v = p0[(size_t)b * PREc + kx];
            else {
              kx -= PREc;
              if (kx < 256)
                v = ldF(p1 + (size_t)b * s1 + kx);
              else {
                kx -= 256;
                if (kx < DECc)
                  v = ldF(p2 + (size_t)b * s2_ + kx);
                else
                  v = ldF(p3 + (size_t)b * s3 + (kx - DECc));
              }
            }
            xs[bi][kk] = v;
          }
        }
      }
      __syncthreads();
      float4 acc[4];
#pragma unroll
      for (int i = 0; i < 4; ++i) acc[i] = make_float4(0.f, 0.f, 0.f, 0.f);
      const float4* Wp = W4 + (size_t)k0 * 512 + nc * 64 + ct;
      int kl4 = klen >> 2;
#pragma unroll 2
      for (int k4 = 0; k4 < kl4; ++k4) {
        float4 xv[4];
#pragma unroll
        for (int bi = 0; bi < 4; ++bi) xv[bi] = *(const float4*)&xs[bsub * 4 + bi][k4 * 4];
#pragma unroll
        for (int q = 0; q < 4; ++q) {
          float4 w = Wp[(size_t)(k4 * 4 + q) * 512];
#pragma unroll
          for (int bi = 0; bi < 4; ++bi) {
            float xq = (q == 0) ? xv[bi].x : (q == 1) ? xv[bi].y : (q == 2) ? xv[bi].z : xv[bi].w;
            acc[bi].x += w.x * xq;
            acc[bi].y += w.y * xq;
            acc[bi].z += w.z * xq;
            acc[bi].w += w.w * xq;
          }
        }
      }
      float* zp = P.zX + ((size_t)c * NB + bg * 16 + bsub * 4) * 2048 + nc * 256 + ct * 4;
#pragma unroll
      for (int bi = 0; bi < 4; ++bi) {
        stF2(zp + (size_t)bi * 2048, make_float2(acc[bi].x, acc[bi].y));
        stF2(zp + (size_t)bi * 2048 + 2, make_float2(acc[bi].z, acc[bi].w));
      }
    }
    gbarF(P.flags, ++ep, DBLK);
    // ================= Y phase =================
    if (bid < 64) {  // gate1 for step t+1 (one block per batch, 2 cols/thread)
      int sg = t + 1;
      if (sg >= 0 && sg < NT) {
        bool z = (sg == 0);
        do_gate(P.zX, 0, 5, P.b_rnn1,
                z ? P.zerob : P.c1 + (size_t)((sg - 1) & 1) * NB * 512,
                z ? P.zerob : P.h1 + (size_t)((sg - 1) & 1) * NB * 512, z,
                P.mel_mask + (size_t)sg * NB,
                P.h1 + (size_t)(sg & 1) * NB * 512,
                P.c1 + (size_t)(sg & 1) * NB * 512, bid, 2 * tid);
      }
    } else if (bid < 128) {  // gate2 for step t
      if (t >= 0) {
        bool z = (t == 0);
        do_gate(P.zX, 10, 15, P.b_rnn2,
                z ? P.zerob : P.c2 + (size_t)((t - 1) & 1) * NB * 512,
                z ? P.zerob : P.outs + (size_t)(t - 1) * NB * 512, z,
                P.mel_mask + (size_t)t * NB,
                P.outs + (size_t)t * NB * 512,
                P.c2 + (size_t)(t & 1) * NB * 512, bid - 64, 2 * tid);
      }
    } else if (bid < 192) {  // attention for step t+2 (one block per batch)
      int sa = t + 2;
      if (sa >= 0 && sa < NT) {
        int b = bid - 128;
        float* ah_s = sh;
        float* red_s = sh + 512;
        float* pr_s = sh + 768;
        float* abk = sh + 800;
        float* phi_s = sh + 896;
        float m = P.mel_mask[(size_t)sa * NB + b];
        bool z = (sa == 0);
        int pp = (sa - 1) & 1;
        {
          int j = 2 * tid;
          float2 zi = *(const float2*)(P.b_att + j);
          float2 zf = *(const float2*)(P.b_att + 512 + j);
          float2 zg = *(const float2*)(P.b_att + 1024 + j);
          float2 zo = *(const float2*)(P.b_att + 1536 + j);
          for (int cc = 6; cc <= 9; ++cc) {
            const float* q = P.zX + ((size_t)cc * NB + b) * 2048 + j;
            float2 a = ldF2(q), f2 = ldF2(q + 512), g2 = ldF2(q + 1024), o2 = ldF2(q + 1536);
            zi.x += a.x; zi.y += a.y;
            zf.x += f2.x; zf.y += f2.y;
            zg.x += g2.x; zg.y += g2.y;
            zo.x += o2.x; zo.y += o2.y;
          }
          float2 cp = z ? make_float2(0.f, 0.f)
                        : ldF2(P.ac + (size_t)pp * NB * 512 + (size_t)b * 512 + j);
          float2 hp = z ? make_float2(0.f, 0.f)
                        : ldF2(P.ah + (size_t)pp * NB * 512 + (size_t)b * 512 + j);
          float cnx = sigm(zf.x) * cp.x + sigm(zi.x) * tanhf(zg.x);
          float cny = sigm(zf.y) * cp.y + sigm(zi.y) * tanhf(zg.y);
          float hrx = sigm(zo.x) * tanhf(cnx);
          float hry = sigm(zo.y) * tanhf(cny);
          ah_s[j] = hrx;
          ah_s[j + 1] = hry;
          stF2(P.ah + (size_t)(sa & 1) * NB * 512 + (size_t)b * 512 + j,
               make_float2(m * hrx + (1.f - m) * hp.x, m * hry + (1.f - m) * hp.y));
          stF2(P.ac + (size_t)(sa & 1) * NB * 512 + (size_t)b * 512 + j,
               make_float2(m * cnx + (1.f - m) * cp.x, m * cny + (1.f - m) * cp.y));
        }
        __syncthreads();
        {
          int cc2 = tid & 31, ch = tid >> 5;
          float ssum = 0.f;
          if (cc2 < 30)
            for (int k = ch * 64; k < ch * 64 + 64; ++k) ssum += ah_s[k] * P.w_proj[k * 30 + cc2];
          red_s[ch * 32 + cc2] = ssum;
        }
        __syncthreads();
        if (tid < 30) {
          float ssum = P.b_proj[tid];
          for (int ch = 0; ch < 8; ++ch) ssum += red_s[ch * 32 + tid];
          pr_s[tid] = ssum;
        }
        __syncthreads();
        if (tid < WMc) {
          float kp = z ? 0.f : ldF(P.ak + (size_t)pp * NB * AKS + (size_t)b * AKS + tid);
          float a_t = softplusf(pr_s[tid]);
          float b_t = softplusf(pr_s[WMc + tid]);
          float k_t = kp + softplusf(pr_s[2 * WMc + tid]);
          abk[tid] = a_t;
          abk[32 + tid] = b_t;
          abk[64 + tid] = k_t;
          stF(P.ak + (size_t)(sa & 1) * NB * AKS + (size_t)b * AKS + tid,
              m * k_t + (1.f - m) * kp);
        }
        __syncthreads();
        {
          int u = tid;
          float ssum = 0.f;
#pragma unroll
          for (int gg = 0; gg < WMc; ++gg) {
            float dd = abk[64 + gg] - (float)u;
            ssum += abk[gg] * expf(-abk[32 + gg] * dd * dd);
          }
          phi_s[u] = ssum * P.text_mask[u * NB + b];
        }
        __syncthreads();
        {
          int dcol = tid;
          float ssum = 0.f;
#pragma unroll 8
          for (int u = 0; u < NU; ++u)
            ssum += phi_s[u] *
                    __builtin_nontemporal_load(P.ctx + ((size_t)u * NB + b) * 256 + dcol);
          float wprev = z ? 0.f : ldF(P.aw + (size_t)pp * NB * 256 + (size_t)b * 256 + dcol);
          stF(P.aw + (size_t)(sa & 1) * NB * 256 + (size_t)b * 256 + dcol,
              m * ssum + (1.f - m) * wprev);
        }
      }
    }
    gbarF(P.flags, ++ep, DBLK);
  }
}

// =====================================================================================
extern "C" void kernel_launch(void* const* d_in, const int* in_sizes, int n_in,
                              void* d_out, int out_size, void* d_ws, size_t ws_size,
                              hipStream_t stream) {
  const float* in_mels = (const float*)d_in[0];
  const float* mel_mask = (const float*)d_in[1];
  const int* text = (const int*)d_in[2];
  const float* text_mask = (const float*)d_in[3];
  const float* w_pre1 = (const float*)d_in[4];
  const float* b_pre1 = (const float*)d_in[5];
  const float* w_pre2 = (const float*)d_in[6];
  const float* b_pre2 = (const float*)d_in[7];
  const float* emb = (const float*)d_in[8];
  const float* conv_w0 = (const float*)d_in[9];
  const float* conv_b0 = (const float*)d_in[10];
  const float* conv_w1 = (const float*)d_in[11];
  const float* conv_b1 = (const float*)d_in[12];
  const float* conv_w2 = (const float*)d_in[13];
  const float* conv_b2 = (const float*)d_in[14];
  const float* w_bif = (const float*)d_in[15];
  const float* b_bif = (const float*)d_in[16];
  const float* w_bib = (const float*)d_in[17];
  const float* b_bib = (const float*)d_in[18];
  const float* w_att = (const float*)d_in[19];
  const float* b_att = (const float*)d_in[20];
  const float* w_proj = (const float*)d_in[21];
  const float* b_proj = (const float*)d_in[22];
  const float* w_rnn1 = (const float*)d_in[23];
  const float* b_rnn1 = (const float*)d_in[24];
  const float* w_rnn2 = (const float*)d_in[25];
  const float* b_rnn2 = (const float*)d_in[26];
  const float* w_outp = (const float*)d_in[27];
  const float* b_outp = (const float*)d_in[28];

  float* ws = (float*)d_ws;
  size_t off = 0;
  auto alloc = [&](size_t n) {
    float* p = ws + off;
    off += (n + 63) & ~(size_t)63;
    return p;
  };
  float* corr = alloc((size_t)NT * NB * PREc);
  float* embx = alloc((size_t)NB * NU * EMBc);
  float* zX = alloc((size_t)16 * NB * 2048);       // decoder partials; also conv ping / prenet tmp
  float* ctx = alloc((size_t)NU * NB * 2 * ENCc);  // also conv pong
  float* zE = alloc((size_t)2 * 8 * NB * 512);
  float* hbufE = alloc((size_t)4 * NB * ENCc);
  float* cbufE = alloc((size_t)4 * NB * ENCc);
  float* aw = alloc((size_t)2 * NB * 2 * ENCc);
  float* ak = alloc((size_t)2 * NB * AKS);
  float* ah = alloc((size_t)2 * NB * DECc);
  float* ac = alloc((size_t)2 * NB * DECc);
  float* h1 = alloc((size_t)2 * NB * DECc);
  float* c1 = alloc((size_t)2 * NB * DECc);
  float* c2 = alloc((size_t)2 * NB * DECc);
  float* outs = alloc((size_t)NT * NB * DECc);  // h2 rows; front also conv output
  float* weff0 = alloc((size_t)5 * EMBc * NFc);
  float* beff0 = alloc(NFc);
  float* weff1 = alloc((size_t)5 * NFc * NFc);
  float* beff1 = alloc(NFc);
  float* weff2 = alloc((size_t)5 * NFc * NFc);
  float* beff2 = alloc(NFc);
  float* zerob = alloc(1024);
  float* barf = alloc(1024);  // flag arrays (4 KB)
  unsigned* bars = (unsigned*)barf;
  unsigned* dflags = bars;        // 512 decoder flags
  unsigned* eflags = bars + 640;  // 128 encoder flags

  float* convA = zX;
  float* convB = ctx;
  float* convOut = outs;
  float* tmp = zX;

  hipMemsetAsync(zerob, 0, 1024 * sizeof(float), stream);
  hipMemsetAsync(bars, 0, 1024 * sizeof(float), stream);

  // ---- prenet ----
  k_dense<NMELc, PREc, 8><<<NT * NB / 8, 128, 0, stream>>>(in_mels, w_pre1, b_pre1, tmp, NT * NB);
  k_dense<PREc, PREc, 8><<<NT * NB / 8, 128, 0, stream>>>(tmp, w_pre2, b_pre2, corr, NT * NB);

  // ---- text conv stacks: embx -> convB -> convA -> convOut ----
  k_embed<<<(NB * NU * EMBc + 255) / 256, 256, 0, stream>>>(text, emb, embx);
  k_weff<EMBc><<<(5 * EMBc * NFc + 255) / 256, 256, 0, stream>>>(conv_w0, conv_b0, weff0, beff0);
  k_weff<NFc><<<(5 * NFc * NFc + 255) / 256, 256, 0, stream>>>(conv_w1, conv_b1, weff1, beff1);
  k_weff<NFc><<<(5 * NFc * NFc + 255) / 256, 256, 0, stream>>>(conv_w2, conv_b2, weff2, beff2);
  k_conv<EMBc, false><<<dim3(NU / 8, NB), 128, 0, stream>>>(embx, weff0, beff0, convB);
  k_conv<NFc, true><<<dim3(NU / 8, NB), 128, 0, stream>>>(convB, weff1, beff1, convA);
  k_conv<NFc, true><<<dim3(NU / 8, NB), 128, 0, stream>>>(convA, weff2, beff2, convOut);

  // ---- persistent encoder ----
  {
    EncP E;
    E.Wf = w_bif; E.bf = b_bif; E.Wb = w_bib; E.bb = b_bib;
    E.convt = convOut; E.text_mask = text_mask;
    E.ctx = ctx; E.hbuf = hbufE; E.cbuf = cbufE; E.zE = zE;
    E.flags = eflags;
    k_encP<<<EBLK, 128, 0, stream>>>(E);
  }

  // ---- persistent decoder ----
  {
    DecP D;
    D.corr = corr; D.mel_mask = mel_mask; D.text_mask = text_mask; D.ctx = ctx;
    D.w_att = w_att; D.b_att = b_att;
    D.w_rnn1 = w_rnn1; D.b_rnn1 = b_rnn1;
    D.w_rnn2 = w_rnn2; D.b_rnn2 = b_rnn2;
    D.w_proj = w_proj; D.b_proj = b_proj;
    D.zX = zX; D.aw = aw; D.ak = ak; D.ah = ah; D.ac = ac;
    D.h1 = h1; D.c1 = c1; D.c2 = c2; D.outs = outs; D.zerob = zerob;
    D.flags = dflags;
    k_decP<<<DBLK, 256, 0, stream>>>(D);
  }

  // ---- output projection ----
  k_dense<DECc, NMELc, 8><<<NT * NB / 8, 128, 0, stream>>>(outs, w_outp, b_outp, (float*)d_out,
                                                           NT * NB);
}

// Round 8
// 47988.007 us; speedup vs baseline: 1.0473x; 1.0473x over previous
//
#include <hip/hip_runtime.h>
#include <math.h>

constexpr int NB    = 64;
constexpr int NT    = 256;
constexpr int NU    = 256;
constexpr int NMELc = 80;
constexpr int PREc  = 128;
constexpr int EMBc  = 15;
constexpr int NFc   = 128;
constexpr int ENCc  = 128;
constexpr int DECc  = 512;
constexpr int WMc   = 10;
constexpr int AKS   = 16;
constexpr int DBLK  = 512;   // decoder persistent grid (2 blocks/CU)
constexpr int EBLK  = 128;   // encoder persistent grid

__device__ __forceinline__ float sigm(float x) { return 1.0f / (1.0f + expf(-x)); }
__device__ __forceinline__ float softplusf(float x) { return fmaxf(x, 0.0f) + log1pf(expf(-fabsf(x))); }

// ---- relaxed agent-scope (cache-bypassing, fence-free) accessors ----
__device__ __forceinline__ float ldF(const float* p) {
  return __hip_atomic_load(p, __ATOMIC_RELAXED, __HIP_MEMORY_SCOPE_AGENT);
}
__device__ __forceinline__ void stF(float* p, float v) {
  __hip_atomic_store(p, v, __ATOMIC_RELAXED, __HIP_MEMORY_SCOPE_AGENT);
}
__device__ __forceinline__ float2 ldF2(const float* p) {
  unsigned long long u = __hip_atomic_load((const unsigned long long*)p, __ATOMIC_RELAXED,
                                           __HIP_MEMORY_SCOPE_AGENT);
  return __builtin_bit_cast(float2, u);
}
__device__ __forceinline__ void stF2(float* p, float2 v) {
  __hip_atomic_store((unsigned long long*)p, __builtin_bit_cast(unsigned long long, v),
                     __ATOMIC_RELAXED, __HIP_MEMORY_SCOPE_AGENT);
}
__device__ __forceinline__ unsigned ldU(const unsigned* p) {
  return __hip_atomic_load(p, __ATOMIC_RELAXED, __HIP_MEMORY_SCOPE_AGENT);
}
__device__ __forceinline__ void stU(unsigned* p, unsigned v) {
  __hip_atomic_store(p, v, __ATOMIC_RELAXED, __HIP_MEMORY_SCOPE_AGENT);
}
__device__ __forceinline__ void vdrain() { asm volatile("s_waitcnt vmcnt(0)" ::: "memory"); }

// ---- centralized flag barrier: store-only arrival, ONE scanner wave, sleep-paced 1-word polls ----
// flags[bid] monotone epochs. Block 0 wave 0 scans; publishes to nblk/64 replicated release
// words (16-word spacing = separate cachelines). Others poll their group's word only.
__device__ __forceinline__ void gbarC(unsigned* flags, unsigned* rel, unsigned e, int nblk) {
  __syncthreads();  // emits waitcnt vmcnt(0): prior bypass stores at L3 before arrival
  if (threadIdx.x == 0) stU(&flags[blockIdx.x], e);
  if (blockIdx.x == 0) {
    if (threadIdx.x < 64) {
      bool ok;
      do {
        ok = true;
        for (int i = threadIdx.x; i < nblk; i += 64) ok &= (ldU(&flags[i]) >= e);
      } while (!__all(ok));
    }
    __syncthreads();
    if ((int)threadIdx.x < (nblk >> 6)) stU(&rel[threadIdx.x * 16], e);
  } else if (threadIdx.x == 0) {
    const unsigned* myrel = &rel[(blockIdx.x >> 6) * 16];
    while (ldU(myrel) < e) __builtin_amdgcn_s_sleep(16);
  }
  __syncthreads();
}

// ---------------- generic dense ----------------
template <int K, int N, int RB>
__global__ void k_dense(const float* __restrict__ X, const float* __restrict__ W,
                        const float* __restrict__ bias, float* __restrict__ Y, int R) {
  __shared__ float xs[RB][K];
  int r0 = blockIdx.x * RB;
  int tid = threadIdx.x;  // 128
  for (int idx = tid; idx < RB * K; idx += 128) {
    int r = idx / K, k = idx % K;
    xs[r][k] = (r0 + r < R) ? X[(size_t)(r0 + r) * K + k] : 0.0f;
  }
  __syncthreads();
  int j = tid;
  if (j >= N) return;
  float acc[RB];
#pragma unroll
  for (int r = 0; r < RB; ++r) acc[r] = 0.f;
  for (int k = 0; k < K; ++k) {
    float w = W[(size_t)k * N + j];
#pragma unroll
    for (int r = 0; r < RB; ++r) acc[r] += xs[r][k] * w;
  }
  float bj = bias[j];
  for (int r = 0; r < RB; ++r)
    if (r0 + r < R) Y[(size_t)(r0 + r) * N + j] = acc[r] + bj;
}

// ---------------- embedding gather ----------------
__global__ void k_embed(const int* __restrict__ text, const float* __restrict__ emb,
                        float* __restrict__ out) {
  int idx = blockIdx.x * blockDim.x + threadIdx.x;
  if (idx >= NB * NU * EMBc) return;
  int c = idx % EMBc;
  int bu = idx / EMBc;
  int u = bu % NU, b = bu / NU;
  out[idx] = emb[text[u * NB + b] * EMBc + c];
}

// ---------------- merged conv weights ----------------
template <int CIN>
__global__ void k_weff(const float* __restrict__ w, const float* __restrict__ bb,
                       float* __restrict__ weff, float* __restrict__ beff) {
  int idx = blockIdx.x * blockDim.x + threadIdx.x;
  const int tot = 5 * CIN * NFc;
  if (idx < tot) {
    int f = idx % NFc;
    int tc = idx / NFc;
    int c = tc % CIN, t = tc / CIN;
    float m0 = (t == 2) ? 1.f : 0.f;
    float m1 = (t >= 1 && t <= 3) ? 1.f : 0.f;
    float w0 = w[((size_t)(0 * 5 + t) * CIN + c) * NFc + f];
    float w1 = w[((size_t)(1 * 5 + t) * CIN + c) * NFc + f];
    float w2 = w[((size_t)(2 * 5 + t) * CIN + c) * NFc + f];
    weff[idx] = w0 * m0 + w1 * m1 + w2;
  }
  if (idx < NFc) beff[idx] = bb[idx] + bb[NFc + idx] + bb[2 * NFc + idx];
}

// ---------------- conv stack ----------------
template <int CIN, bool RES>
__global__ void k_conv(const float* __restrict__ x, const float* __restrict__ weff,
                       const float* __restrict__ beff, float* __restrict__ y) {
  const int UT = 8;
  __shared__ float xs[(UT + 4) * CIN];
  int b = blockIdx.y, u0 = blockIdx.x * UT;
  int tid = threadIdx.x;  // 128
  for (int idx = tid; idx < (UT + 4) * CIN; idx += 128) {
    int c = idx % CIN;
    int uu = idx / CIN;
    int u = u0 + uu - 2;
    xs[idx] = (u >= 0 && u < NU) ? x[((size_t)b * NU + u) * CIN + c] : 0.f;
  }
  __syncthreads();
  int f = tid;
  float acc[UT];
#pragma unroll
  for (int r = 0; r < UT; ++r) acc[r] = beff[f];
  for (int t = 0; t < 5; ++t)
    for (int c = 0; c < CIN; ++c) {
      float w = weff[((size_t)t * CIN + c) * NFc + f];
#pragma unroll
      for (int r = 0; r < UT; ++r) acc[r] += xs[(r + t) * CIN + c] * w;
    }
  for (int r = 0; r < UT; ++r) {
    float v = fmaxf(acc[r], 0.f);
    if (RES) v += xs[(r + 2) * CIN + f];
    y[((size_t)b * NU + u0 + r) * NFc + f] = v;
  }
}

// ---------------- persistent encoder BiLSTM ----------------
struct EncP {
  const float *Wf, *bf, *Wb, *bb, *convt, *text_mask;
  float *ctx, *hbuf, *cbuf, *zE;
  unsigned *flags, *rel;
};
__global__ __launch_bounds__(128, 2) void k_encP(EncP P) {
  const size_t ZPS = (size_t)8 * NB * 512;
  __shared__ float hs[4][128];
  __shared__ float xs[4][64];
  int tid = threadIdx.x;
  int bid = blockIdx.x;
  int d = bid >> 6;
  int q = (bid >> 4) & 3;
  int g = bid & 15;
  int b0 = g * 4;
  const float* Wd = d ? P.Wb : P.Wf;
  const float* bd = d ? P.bb : P.bf;
  int j = tid;
  unsigned ep = 0;
  for (int u = 0; u <= NU; ++u) {
    if (u > 0) {
      int ig = u - 1;
      int upos = d ? (NU - 1 - ig) : ig;
      const float* zr = P.zE + (size_t)((u - 1) & 1) * ZPS + (size_t)d * 4 * NB * 512;
      for (int bi = 0; bi < 4; ++bi) {
        int b = b0 + bi;
        float zi = bd[j], zf = bd[128 + j], zg = bd[256 + j], zo = bd[384 + j];
        for (int qq = 0; qq < 4; ++qq) {
          const float* p = zr + ((size_t)qq * NB + b) * 512;
          zi += ldF(p + j);
          zf += ldF(p + 128 + j);
          zg += ldF(p + 256 + j);
          zo += ldF(p + 384 + j);
        }
        float cp = 0.f, hp = 0.f;
        if (u >= 2) {
          cp = ldF(P.cbuf + ((size_t)(d * 2 + (u & 1)) * NB + b) * 128 + j);
          hp = ldF(P.hbuf + ((size_t)(d * 2 + (u & 1)) * NB + b) * 128 + j);
        }
        float cn = sigm(zf) * cp + sigm(zi) * tanhf(zg);
        float hn = sigm(zo) * tanhf(cn);
        float mt = P.text_mask[upos * NB + b];
        hn = mt * hn + (1.f - mt) * hp;
        cn = mt * cn + (1.f - mt) * cp;
        hs[bi][j] = hn;
        if (q == 0) {
          stF(P.hbuf + ((size_t)(d * 2 + ((u - 1) & 1)) * NB + b) * 128 + j, hn);
          stF(P.cbuf + ((size_t)(d * 2 + ((u - 1) & 1)) * NB + b) * 128 + j, cn);
          P.ctx[((size_t)upos * NB + b) * 256 + d * 128 + j] = hn;  // consumed by next kernel
        }
      }
    } else {
#pragma unroll
      for (int bi = 0; bi < 4; ++bi) hs[bi][j] = 0.f;
    }
    if (u < NU) {
      __syncthreads();
      int k0 = q * 64;
      {
        int upos_x = d ? (NU - 1 - u) : u;
        for (int idx = tid; idx < 4 * 64; idx += 128) {
          int bi = idx >> 6, kk = idx & 63;
          int k = k0 + kk;
          float v = (k < 128) ? P.convt[((size_t)(b0 + bi) * NU + upos_x) * 128 + k]
                              : hs[bi][k - 128];
          xs[bi][kk] = v;
        }
      }
      __syncthreads();
      float4 acc[4];
#pragma unroll
      for (int bi = 0; bi < 4; ++bi) acc[bi] = make_float4(0.f, 0.f, 0.f, 0.f);
      const float4* Wp = (const float4*)Wd + (size_t)k0 * 128 + tid;
#pragma unroll 8
      for (int kk = 0; kk < 64; ++kk) {
        float4 w = Wp[(size_t)kk * 128];
#pragma unroll
        for (int bi = 0; bi < 4; ++bi) {
          float xv = xs[bi][kk];
          acc[bi].x += w.x * xv;
          acc[bi].y += w.y * xv;
          acc[bi].z += w.z * xv;
          acc[bi].w += w.w * xv;
        }
      }
      float* zwf = P.zE + (size_t)(u & 1) * ZPS + ((size_t)(d * 4 + q) * NB + b0) * 512 + tid * 4;
#pragma unroll
      for (int bi = 0; bi < 4; ++bi) {
        stF2(zwf + (size_t)bi * 512, make_float2(acc[bi].x, acc[bi].y));
        stF2(zwf + (size_t)bi * 512 + 2, make_float2(acc[bi].z, acc[bi].w));
      }
    }
    gbarC(P.flags, P.rel, ++ep, EBLK);
  }
}

// ---------------- persistent decoder ----------------
// Chunks (16): c 0..5 -> z1 (K=1408: 5x240+208), c 6..9 -> za (K=896: 4x224),
//              c 10..15 -> z2 (5x240+208).
// X block decode: bg = bid>>7 (16 batches each), r = bid&127, c = r>>3, nc = r&7.
// Same (c,nc) blocks are 128 apart (same XCD): per-XCD weight slice ~3.75MB, L2-resident.
// X(t): z2(t), z1(t+1), za(t+2).  Y(t): gate2(t), gate1(t+1), att(t+2).
struct DecP {
  const float *corr, *mel_mask, *text_mask, *ctx;
  const float *w_att, *b_att, *w_rnn1, *b_rnn1, *w_rnn2, *b_rnn2, *w_proj, *b_proj;
  float *zX, *aw, *ak, *ah, *ac, *h1, *c1, *c2, *outs, *zerob;
  unsigned *flags, *rel;
};

__device__ __forceinline__ void do_gate(const float* zX, int clo, int chi, const float* bias,
                                        const float* cprev, const float* hprev, bool zfirst,
                                        const float* mm, float* hout, float* cout, int b, int j) {
  float2 zi = *(const float2*)(bias + j);
  float2 zf = *(const float2*)(bias + 512 + j);
  float2 zg = *(const float2*)(bias + 1024 + j);
  float2 zo = *(const float2*)(bias + 1536 + j);
  for (int c = clo; c <= chi; ++c) {
    const float* q = zX + ((size_t)c * NB + b) * 2048 + j;
    float2 a = ldF2(q), f2 = ldF2(q + 512), g2 = ldF2(q + 1024), o2 = ldF2(q + 1536);
    zi.x += a.x; zi.y += a.y;
    zf.x += f2.x; zf.y += f2.y;
    zg.x += g2.x; zg.y += g2.y;
    zo.x += o2.x; zo.y += o2.y;
  }
  float2 cp = zfirst ? make_float2(0.f, 0.f) : ldF2(cprev + (size_t)b * 512 + j);
  float2 hp = zfirst ? make_float2(0.f, 0.f) : ldF2(hprev + (size_t)b * 512 + j);
  float m = mm[b];
  float cnx = sigm(zf.x) * cp.x + sigm(zi.x) * tanhf(zg.x);
  float cny = sigm(zf.y) * cp.y + sigm(zi.y) * tanhf(zg.y);
  float hnx = sigm(zo.x) * tanhf(cnx);
  float hny = sigm(zo.y) * tanhf(cny);
  stF2(hout + (size_t)b * 512 + j, make_float2(m * hnx + (1.f - m) * hp.x,
                                               m * hny + (1.f - m) * hp.y));
  stF2(cout + (size_t)b * 512 + j, make_float2(m * cnx + (1.f - m) * cp.x,
                                               m * cny + (1.f - m) * cp.y));
}

__global__ __launch_bounds__(256, 2) void k_decP(DecP P) {
  __shared__ float xs[16][240];
  float* sh = &xs[0][0];
  int tid = threadIdx.x, bid = blockIdx.x;
  int bg = bid >> 7, r = bid & 127, c = r >> 3, nc = r & 7;
  int g, k0, klen;
  if (c < 6)       { g = 0; k0 = c * 240;        klen = (c == 5)  ? 208 : 240; }
  else if (c < 10) { g = 1; k0 = (c - 6) * 224;  klen = 224; }
  else             { g = 2; k0 = (c - 10) * 240; klen = (c == 15) ? 208 : 240; }
  const float* Wg = (g == 0) ? P.w_rnn1 : (g == 1 ? P.w_att : P.w_rnn2);
  const float4* W4 = (const float4*)Wg;
  int bsub = tid >> 6, ct = tid & 63;
  unsigned ep = 0;
  for (int t = -2; t < NT; ++t) {
    // ================= X phase =================
    int s = (g == 0) ? (t + 1) : (g == 1 ? (t + 2) : t);
    if (s >= 0 && s < NT) {
      const float* p0 = P.corr + (size_t)s * NB * PREc;
      const float *p1, *p2, *p3;
      int s1, s2_, s3;
      if (g == 1) {  // za(s): [corr_s, aw(s-1), ah(s-1)]
        bool z = (s == 0);
        int pp = (s - 1) & 1;
        p1 = z ? P.zerob : P.aw + (size_t)pp * NB * 256; s1 = z ? 0 : 256;
        p2 = z ? P.zerob : P.ah + (size_t)pp * NB * DECc; s2_ = z ? 0 : DECc;
        p3 = P.zerob; s3 = 0;
      } else if (g == 0) {  // z1(s): [corr_s, aw(s), ah(s), h1(s-1)]
        int pp = s & 1;
        p1 = P.aw + (size_t)pp * NB * 256; s1 = 256;
        p2 = P.ah + (size_t)pp * NB * DECc; s2_ = DECc;
        bool z = (s == 0);
        p3 = z ? P.zerob : P.h1 + (size_t)((s - 1) & 1) * NB * DECc; s3 = z ? 0 : DECc;
      } else {  // z2(s): [corr_s, aw(s), h1(s), h2(s-1)]
        int pp = s & 1;
        p1 = P.aw + (size_t)pp * NB * 256; s1 = 256;
        p2 = P.h1 + (size_t)pp * NB * DECc; s2_ = DECc;
        bool z = (s == 0);
        p3 = z ? P.zerob : P.outs + (size_t)(s - 1) * NB * DECc; s3 = z ? 0 : DECc;
      }
      // stage x: one row per pass, kk = tid -> global loads coalesced, LDS conflict-free
      {
        int kk = tid;
        if (kk < klen) {
          int k = k0 + kk;
#pragma unroll 4
          for (int bi = 0; bi < 16; ++bi) {
            int b = bg * 16 + bi;
            float v;
            int kx = k;
            if (kx < PREc)
              v = p0[(size_t)b * PREc + kx];
            else {
              kx -= PREc;
              if (kx < 256)
                v = ldF(p1 + (size_t)b * s1 + kx);
              else {
                kx -= 256;
                if (kx < DECc)
                  v = ldF(p2 + (size_t)b * s2_ + kx);
                else
                  v = ldF(p3 + (size_t)b * s3 + (kx - DECc));
              }
            }
            xs[bi][kk] = v;
          }
        }
      }
      __syncthreads();
      float4 acc[4];
#pragma unroll
      for (int i = 0; i < 4; ++i) acc[i] = make_float4(0.f, 0.f, 0.f, 0.f);
      const float4* Wp = W4 + (size_t)k0 * 512 + nc * 64 + ct;
      int kl4 = klen >> 2;
#pragma unroll 2
      for (int k4 = 0; k4 < kl4; ++k4) {
        float4 xv[4];
#pragma unroll
        for (int bi = 0; bi < 4; ++bi) xv[bi] = *(const float4*)&xs[bsub * 4 + bi][k4 * 4];
#pragma unroll
        for (int q = 0; q < 4; ++q) {
          float4 w = Wp[(size_t)(k4 * 4 + q) * 512];
#pragma unroll
          for (int bi = 0; bi < 4; ++bi) {
            float xq = (q == 0) ? xv[bi].x : (q == 1) ? xv[bi].y : (q == 2) ? xv[bi].z : xv[bi].w;
            acc[bi].x += w.x * xq;
            acc[bi].y += w.y * xq;
            acc[bi].z += w.z * xq;
            acc[bi].w += w.w * xq;
          }
        }
      }
      float* zp = P.zX + ((size_t)c * NB + bg * 16 + bsub * 4) * 2048 + nc * 256 + ct * 4;
#pragma unroll
      for (int bi = 0; bi < 4; ++bi) {
        stF2(zp + (size_t)bi * 2048, make_float2(acc[bi].x, acc[bi].y));
        stF2(zp + (size_t)bi * 2048 + 2, make_float2(acc[bi].z, acc[bi].w));
      }
    }
    gbarC(P.flags, P.rel, ++ep, DBLK);
    // ================= Y phase =================
    if (bid < 64) {  // gate1 for step t+1 (one block per batch, 2 cols/thread)
      int sg = t + 1;
      if (sg >= 0 && sg < NT) {
        bool z = (sg == 0);
        do_gate(P.zX, 0, 5, P.b_rnn1,
                z ? P.zerob : P.c1 + (size_t)((sg - 1) & 1) * NB * 512,
                z ? P.zerob : P.h1 + (size_t)((sg - 1) & 1) * NB * 512, z,
                P.mel_mask + (size_t)sg * NB,
                P.h1 + (size_t)(sg & 1) * NB * 512,
                P.c1 + (size_t)(sg & 1) * NB * 512, bid, 2 * tid);
      }
    } else if (bid < 128) {  // gate2 for step t
      if (t >= 0) {
        bool z = (t == 0);
        do_gate(P.zX, 10, 15, P.b_rnn2,
                z ? P.zerob : P.c2 + (size_t)((t - 1) & 1) * NB * 512,
                z ? P.zerob : P.outs + (size_t)(t - 1) * NB * 512, z,
                P.mel_mask + (size_t)t * NB,
                P.outs + (size_t)t * NB * 512,
                P.c2 + (size_t)(t & 1) * NB * 512, bid - 64, 2 * tid);
      }
    } else if (bid < 192) {  // attention for step t+2 (one block per batch)
      int sa = t + 2;
      if (sa >= 0 && sa < NT) {
        int b = bid - 128;
        float* ah_s = sh;
        float* red_s = sh + 512;
        float* pr_s = sh + 768;
        float* abk = sh + 800;
        float* phi_s = sh + 896;
        float m = P.mel_mask[(size_t)sa * NB + b];
        bool z = (sa == 0);
        int pp = (sa - 1) & 1;
        {
          int j = 2 * tid;
          float2 zi = *(const float2*)(P.b_att + j);
          float2 zf = *(const float2*)(P.b_att + 512 + j);
          float2 zg = *(const float2*)(P.b_att + 1024 + j);
          float2 zo = *(const float2*)(P.b_att + 1536 + j);
          for (int cc = 6; cc <= 9; ++cc) {
            const float* q = P.zX + ((size_t)cc * NB + b) * 2048 + j;
            float2 a = ldF2(q), f2 = ldF2(q + 512), g2 = ldF2(q + 1024), o2 = ldF2(q + 1536);
            zi.x += a.x; zi.y += a.y;
            zf.x += f2.x; zf.y += f2.y;
            zg.x += g2.x; zg.y += g2.y;
            zo.x += o2.x; zo.y += o2.y;
          }
          float2 cp = z ? make_float2(0.f, 0.f)
                        : ldF2(P.ac + (size_t)pp * NB * 512 + (size_t)b * 512 + j);
          float2 hp = z ? make_float2(0.f, 0.f)
                        : ldF2(P.ah + (size_t)pp * NB * 512 + (size_t)b * 512 + j);
          float cnx = sigm(zf.x) * cp.x + sigm(zi.x) * tanhf(zg.x);
          float cny = sigm(zf.y) * cp.y + sigm(zi.y) * tanhf(zg.y);
          float hrx = sigm(zo.x) * tanhf(cnx);
          float hry = sigm(zo.y) * tanhf(cny);
          ah_s[j] = hrx;
          ah_s[j + 1] = hry;
          stF2(P.ah + (size_t)(sa & 1) * NB * 512 + (size_t)b * 512 + j,
               make_float2(m * hrx + (1.f - m) * hp.x, m * hry + (1.f - m) * hp.y));
          stF2(P.ac + (size_t)(sa & 1) * NB * 512 + (size_t)b * 512 + j,
               make_float2(m * cnx + (1.f - m) * cp.x, m * cny + (1.f - m) * cp.y));
        }
        __syncthreads();
        {
          int cc2 = tid & 31, ch = tid >> 5;
          float ssum = 0.f;
          if (cc2 < 30)
            for (int k = ch * 64; k < ch * 64 + 64; ++k) ssum += ah_s[k] * P.w_proj[k * 30 + cc2];
          red_s[ch * 32 + cc2] = ssum;
        }
        __syncthreads();
        if (tid < 30) {
          float ssum = P.b_proj[tid];
          for (int ch = 0; ch < 8; ++ch) ssum += red_s[ch * 32 + tid];
          pr_s[tid] = ssum;
        }
        __syncthreads();
        if (tid < WMc) {
          float kp = z ? 0.f : ldF(P.ak + (size_t)pp * NB * AKS + (size_t)b * AKS + tid);
          float a_t = softplusf(pr_s[tid]);
          float b_t = softplusf(pr_s[WMc + tid]);
          float k_t = kp + softplusf(pr_s[2 * WMc + tid]);
          abk[tid] = a_t;
          abk[32 + tid] = b_t;
          abk[64 + tid] = k_t;
          stF(P.ak + (size_t)(sa & 1) * NB * AKS + (size_t)b * AKS + tid,
              m * k_t + (1.f - m) * kp);
        }
        __syncthreads();
        {
          int u = tid;
          float ssum = 0.f;
#pragma unroll
          for (int gg = 0; gg < WMc; ++gg) {
            float dd = abk[64 + gg] - (float)u;
            ssum += abk[gg] * expf(-abk[32 + gg] * dd * dd);
          }
          phi_s[u] = ssum * P.text_mask[u * NB + b];
        }
        __syncthreads();
        {
          int dcol = tid;
          float ssum = 0.f;
#pragma unroll 8
          for (int u = 0; u < NU; ++u)
            ssum += phi_s[u] *
                    __builtin_nontemporal_load(P.ctx + ((size_t)u * NB + b) * 256 + dcol);
          float wprev = z ? 0.f : ldF(P.aw + (size_t)pp * NB * 256 + (size_t)b * 256 + dcol);
          stF(P.aw + (size_t)(sa & 1) * NB * 256 + (size_t)b * 256 + dcol,
              m * ssum + (1.f - m) * wprev);
        }
      }
    }
    gbarC(P.flags, P.rel, ++ep, DBLK);
  }
}

// =====================================================================================
extern "C" void kernel_launch(void* const* d_in, const int* in_sizes, int n_in,
                              void* d_out, int out_size, void* d_ws, size_t ws_size,
                              hipStream_t stream) {
  const float* in_mels = (const float*)d_in[0];
  const float* mel_mask = (const float*)d_in[1];
  const int* text = (const int*)d_in[2];
  const float* text_mask = (const float*)d_in[3];
  const float* w_pre1 = (const float*)d_in[4];
  const float* b_pre1 = (const float*)d_in[5];
  const float* w_pre2 = (const float*)d_in[6];
  const float* b_pre2 = (const float*)d_in[7];
  const float* emb = (const float*)d_in[8];
  const float* conv_w0 = (const float*)d_in[9];
  const float* conv_b0 = (const float*)d_in[10];
  const float* conv_w1 = (const float*)d_in[11];
  const float* conv_b1 = (const float*)d_in[12];
  const float* conv_w2 = (const float*)d_in[13];
  const float* conv_b2 = (const float*)d_in[14];
  const float* w_bif = (const float*)d_in[15];
  const float* b_bif = (const float*)d_in[16];
  const float* w_bib = (const float*)d_in[17];
  const float* b_bib = (const float*)d_in[18];
  const float* w_att = (const float*)d_in[19];
  const float* b_att = (const float*)d_in[20];
  const float* w_proj = (const float*)d_in[21];
  const float* b_proj = (const float*)d_in[22];
  const float* w_rnn1 = (const float*)d_in[23];
  const float* b_rnn1 = (const float*)d_in[24];
  const float* w_rnn2 = (const float*)d_in[25];
  const float* b_rnn2 = (const float*)d_in[26];
  const float* w_outp = (const float*)d_in[27];
  const float* b_outp = (const float*)d_in[28];

  float* ws = (float*)d_ws;
  size_t off = 0;
  auto alloc = [&](size_t n) {
    float* p = ws + off;
    off += (n + 63) & ~(size_t)63;
    return p;
  };
  float* corr = alloc((size_t)NT * NB * PREc);
  float* embx = alloc((size_t)NB * NU * EMBc);
  float* zX = alloc((size_t)16 * NB * 2048);       // decoder partials; also conv ping / prenet tmp
  float* ctx = alloc((size_t)NU * NB * 2 * ENCc);  // also conv pong
  float* zE = alloc((size_t)2 * 8 * NB * 512);
  float* hbufE = alloc((size_t)4 * NB * ENCc);
  float* cbufE = alloc((size_t)4 * NB * ENCc);
  float* aw = alloc((size_t)2 * NB * 2 * ENCc);
  float* ak = alloc((size_t)2 * NB * AKS);
  float* ah = alloc((size_t)2 * NB * DECc);
  float* ac = alloc((size_t)2 * NB * DECc);
  float* h1 = alloc((size_t)2 * NB * DECc);
  float* c1 = alloc((size_t)2 * NB * DECc);
  float* c2 = alloc((size_t)2 * NB * DECc);
  float* outs = alloc((size_t)NT * NB * DECc);  // h2 rows; front also conv output
  float* weff0 = alloc((size_t)5 * EMBc * NFc);
  float* beff0 = alloc(NFc);
  float* weff1 = alloc((size_t)5 * NFc * NFc);
  float* beff1 = alloc(NFc);
  float* weff2 = alloc((size_t)5 * NFc * NFc);
  float* beff2 = alloc(NFc);
  float* zerob = alloc(1024);
  float* barf = alloc(1024);  // flag arrays (4 KB)
  unsigned* bars = (unsigned*)barf;
  unsigned* dflags = bars;        // 512 decoder arrival flags
  unsigned* drel = bars + 512;    // 8 replicated release words (x16 spacing)
  unsigned* eflags = bars + 672;  // 128 encoder arrival flags
  unsigned* erel = bars + 800;    // 2 replicated release words

  float* convA = zX;
  float* convB = ctx;
  float* convOut = outs;
  float* tmp = zX;

  hipMemsetAsync(zerob, 0, 1024 * sizeof(float), stream);
  hipMemsetAsync(bars, 0, 1024 * sizeof(float), stream);

  // ---- prenet ----
  k_dense<NMELc, PREc, 8><<<NT * NB / 8, 128, 0, stream>>>(in_mels, w_pre1, b_pre1, tmp, NT * NB);
  k_dense<PREc, PREc, 8><<<NT * NB / 8, 128, 0, stream>>>(tmp, w_pre2, b_pre2, corr, NT * NB);

  // ---- text conv stacks: embx -> convB -> convA -> convOut ----
  k_embed<<<(NB * NU * EMBc + 255) / 256, 256, 0, stream>>>(text, emb, embx);
  k_weff<EMBc><<<(5 * EMBc * NFc + 255) / 256, 256, 0, stream>>>(conv_w0, conv_b0, weff0, beff0);
  k_weff<NFc><<<(5 * NFc * NFc + 255) / 256, 256, 0, stream>>>(conv_w1, conv_b1, weff1, beff1);
  k_weff<NFc><<<(5 * NFc * NFc + 255) / 256, 256, 0, stream>>>(conv_w2, conv_b2, weff2, beff2);
  k_conv<EMBc, false><<<dim3(NU / 8, NB), 128, 0, stream>>>(embx, weff0, beff0, convB);
  k_conv<NFc, true><<<dim3(NU / 8, NB), 128, 0, stream>>>(convB, weff1, beff1, convA);
  k_conv<NFc, true><<<dim3(NU / 8, NB), 128, 0, stream>>>(convA, weff2, beff2, convOut);

  // ---- persistent encoder ----
  {
    EncP E;
    E.Wf = w_bif; E.bf = b_bif; E.Wb = w_bib; E.bb = b_bib;
    E.convt = convOut; E.text_mask = text_mask;
    E.ctx = ctx; E.hbuf = hbufE; E.cbuf = cbufE; E.zE = zE;
    E.flags = eflags; E.rel = erel;
    k_encP<<<EBLK, 128, 0, stream>>>(E);
  }

  // ---- persistent decoder ----
  {
    DecP D;
    D.corr = corr; D.mel_mask = mel_mask; D.text_mask = text_mask; D.ctx = ctx;
    D.w_att = w_att; D.b_att = b_att;
    D.w_rnn1 = w_rnn1; D.b_rnn1 = b_rnn1;
    D.w_rnn2 = w_rnn2; D.b_rnn2 = b_rnn2;
    D.w_proj = w_proj; D.b_proj = b_proj;
    D.zX = zX; D.aw = aw; D.ak = ak; D.ah = ah; D.ac = ac;
    D.h1 = h1; D.c1 = c1; D.c2 = c2; D.outs = outs; D.zerob = zerob;
    D.flags = dflags; D.rel = drel;
    k_decP<<<DBLK, 256, 0, stream>>>(D);
  }

  // ---- output projection ----
  k_dense<DECc, NMELc, 8><<<NT * NB / 8, 128, 0, stream>>>(outs, w_outp, b_outp, (float*)d_out,
                                                           NT * NB);
}

// Round 9
// 18128.737 us; speedup vs baseline: 2.7723x; 2.6471x over previous
//
#include <hip/hip_runtime.h>
#include <math.h>

constexpr int NB    = 64;
constexpr int NT    = 256;
constexpr int NU    = 256;
constexpr int NMELc = 80;
constexpr int PREc  = 128;
constexpr int EMBc  = 15;
constexpr int NFc   = 128;
constexpr int ENCc  = 128;
constexpr int DECc  = 512;
constexpr int WMc   = 10;
constexpr int AKS   = 16;

__device__ __forceinline__ float sigm(float x) { return 1.0f / (1.0f + expf(-x)); }
__device__ __forceinline__ float softplusf(float x) { return fmaxf(x, 0.0f) + log1pf(expf(-fabsf(x))); }

// ---------------- generic dense ----------------
template <int K, int N, int RB>
__global__ void k_dense(const float* __restrict__ X, const float* __restrict__ W,
                        const float* __restrict__ bias, float* __restrict__ Y, int R) {
  __shared__ float xs[RB][K];
  int r0 = blockIdx.x * RB;
  int tid = threadIdx.x;  // 128
  for (int idx = tid; idx < RB * K; idx += 128) {
    int r = idx / K, k = idx % K;
    xs[r][k] = (r0 + r < R) ? X[(size_t)(r0 + r) * K + k] : 0.0f;
  }
  __syncthreads();
  int j = tid;
  if (j >= N) return;
  float acc[RB];
#pragma unroll
  for (int r = 0; r < RB; ++r) acc[r] = 0.f;
  for (int k = 0; k < K; ++k) {
    float w = W[(size_t)k * N + j];
#pragma unroll
    for (int r = 0; r < RB; ++r) acc[r] += xs[r][k] * w;
  }
  float bj = bias[j];
  for (int r = 0; r < RB; ++r)
    if (r0 + r < R) Y[(size_t)(r0 + r) * N + j] = acc[r] + bj;
}

// ---------------- embedding gather ----------------
__global__ void k_embed(const int* __restrict__ text, const float* __restrict__ emb,
                        float* __restrict__ out) {
  int idx = blockIdx.x * blockDim.x + threadIdx.x;
  if (idx >= NB * NU * EMBc) return;
  int c = idx % EMBc;
  int bu = idx / EMBc;
  int u = bu % NU, b = bu / NU;
  out[idx] = emb[text[u * NB + b] * EMBc + c];
}

// ---------------- merged conv weights ----------------
template <int CIN>
__global__ void k_weff(const float* __restrict__ w, const float* __restrict__ bb,
                       float* __restrict__ weff, float* __restrict__ beff) {
  int idx = blockIdx.x * blockDim.x + threadIdx.x;
  const int tot = 5 * CIN * NFc;
  if (idx < tot) {
    int f = idx % NFc;
    int tc = idx / NFc;
    int c = tc % CIN, t = tc / CIN;
    float m0 = (t == 2) ? 1.f : 0.f;
    float m1 = (t >= 1 && t <= 3) ? 1.f : 0.f;
    float w0 = w[((size_t)(0 * 5 + t) * CIN + c) * NFc + f];
    float w1 = w[((size_t)(1 * 5 + t) * CIN + c) * NFc + f];
    float w2 = w[((size_t)(2 * 5 + t) * CIN + c) * NFc + f];
    weff[idx] = w0 * m0 + w1 * m1 + w2;
  }
  if (idx < NFc) beff[idx] = bb[idx] + bb[NFc + idx] + bb[2 * NFc + idx];
}

// ---------------- conv stack ----------------
template <int CIN, bool RES>
__global__ void k_conv(const float* __restrict__ x, const float* __restrict__ weff,
                       const float* __restrict__ beff, float* __restrict__ y) {
  const int UT = 8;
  __shared__ float xs[(UT + 4) * CIN];
  int b = blockIdx.y, u0 = blockIdx.x * UT;
  int tid = threadIdx.x;  // 128
  for (int idx = tid; idx < (UT + 4) * CIN; idx += 128) {
    int c = idx % CIN;
    int uu = idx / CIN;
    int u = u0 + uu - 2;
    xs[idx] = (u >= 0 && u < NU) ? x[((size_t)b * NU + u) * CIN + c] : 0.f;
  }
  __syncthreads();
  int f = tid;
  float acc[UT];
#pragma unroll
  for (int r = 0; r < UT; ++r) acc[r] = beff[f];
  for (int t = 0; t < 5; ++t)
    for (int c = 0; c < CIN; ++c) {
      float w = weff[((size_t)t * CIN + c) * NFc + f];
#pragma unroll
      for (int r = 0; r < UT; ++r) acc[r] += xs[(r + t) * CIN + c] * w;
    }
  for (int r = 0; r < UT; ++r) {
    float v = fmaxf(acc[r], 0.f);
    if (RES) v += xs[(r + 2) * CIN + f];
    y[((size_t)b * NU + u0 + r) * NFc + f] = v;
  }
}

// ---------------- encoder BiLSTM fused step (multi-launch, plain loads) ----------------
__global__ __launch_bounds__(128) void k_enc2(int u, int gate_only,
                                              const float* __restrict__ Wf, const float* __restrict__ bf,
                                              const float* __restrict__ Wb, const float* __restrict__ bb_,
                                              const float* __restrict__ convt,
                                              const float* __restrict__ text_mask,
                                              float* __restrict__ ctx, float* __restrict__ hbuf,
                                              float* __restrict__ cbuf, float* __restrict__ zE) {
  const size_t ZPS = (size_t)8 * NB * 512;
  __shared__ float hs[4][128];
  __shared__ float xs[4][64];
  int tid = threadIdx.x;
  int g = blockIdx.x, q = blockIdx.y, d = blockIdx.z;
  int b0 = g * 4;
  const float* Wd = d ? Wb : Wf;
  const float* bd = d ? bb_ : bf;
  int j = tid;
  if (u > 0) {
    int ig = u - 1;
    int upos = d ? (NU - 1 - ig) : ig;
    const float* zr = zE + (size_t)((u - 1) & 1) * ZPS + (size_t)d * 4 * NB * 512;
    for (int bi = 0; bi < 4; ++bi) {
      int b = b0 + bi;
      float zi = bd[j], zf = bd[128 + j], zg = bd[256 + j], zo = bd[384 + j];
      for (int qq = 0; qq < 4; ++qq) {
        const float* p = zr + ((size_t)qq * NB + b) * 512;
        zi += p[j];
        zf += p[128 + j];
        zg += p[256 + j];
        zo += p[384 + j];
      }
      float cp = 0.f, hp = 0.f;
      if (u >= 2) {
        cp = cbuf[((size_t)(d * 2 + (u & 1)) * NB + b) * 128 + j];
        hp = hbuf[((size_t)(d * 2 + (u & 1)) * NB + b) * 128 + j];
      }
      float cn = sigm(zf) * cp + sigm(zi) * tanhf(zg);
      float hn = sigm(zo) * tanhf(cn);
      float mt = text_mask[upos * NB + b];
      hn = mt * hn + (1.f - mt) * hp;
      cn = mt * cn + (1.f - mt) * cp;
      hs[bi][j] = hn;
      if (q == 0) {
        hbuf[((size_t)(d * 2 + ((u - 1) & 1)) * NB + b) * 128 + j] = hn;
        cbuf[((size_t)(d * 2 + ((u - 1) & 1)) * NB + b) * 128 + j] = cn;
        ctx[((size_t)upos * NB + b) * 256 + d * 128 + j] = hn;
      }
    }
  } else {
#pragma unroll
    for (int bi = 0; bi < 4; ++bi) hs[bi][j] = 0.f;
  }
  if (gate_only) return;
  __syncthreads();
  int k0 = q * 64;
  {
    int upos_x = d ? (NU - 1 - u) : u;
    for (int idx = tid; idx < 4 * 64; idx += 128) {
      int bi = idx >> 6, kk = idx & 63;
      int k = k0 + kk;
      float v = (k < 128) ? convt[((size_t)(b0 + bi) * NU + upos_x) * 128 + k] : hs[bi][k - 128];
      xs[bi][kk] = v;
    }
  }
  __syncthreads();
  float4 acc[4];
#pragma unroll
  for (int bi = 0; bi < 4; ++bi) acc[bi] = make_float4(0.f, 0.f, 0.f, 0.f);
  const float4* Wp = (const float4*)Wd + (size_t)k0 * 128 + tid;
#pragma unroll 8
  for (int kk = 0; kk < 64; ++kk) {
    float4 w = Wp[(size_t)kk * 128];
#pragma unroll
    for (int bi = 0; bi < 4; ++bi) {
      float xv = xs[bi][kk];
      acc[bi].x += w.x * xv;
      acc[bi].y += w.y * xv;
      acc[bi].z += w.z * xv;
      acc[bi].w += w.w * xv;
    }
  }
  float4* zw = (float4*)(zE + (size_t)(u & 1) * ZPS) + ((size_t)(d * 4 + q) * NB + b0) * 128 + tid;
#pragma unroll
  for (int bi = 0; bi < 4; ++bi) zw[(size_t)bi * 128] = acc[bi];
}

// ---------------- decoder phase A: all three GEMMs, one launch ----------------
// A(i): za(i) [chunks 6..9], z1(i-1) [chunks 0..5], z2(i-2) [chunks 10..15].
// Grid 512: bid = bg*128 + c*8 + nc (bg siblings 128 apart -> same XCD, weights L2-resident).
// zX layout: [c][b][2048].
struct DecAp {
  const float *corr, *w_rnn1, *w_att, *w_rnn2;
  const float *aw, *ah, *h1, *outs, *zerob;
  float* zX;
};
__global__ __launch_bounds__(256) void k_decA(DecAp P, int i) {
  __shared__ float xs[16][240];
  int tid = threadIdx.x, bid = blockIdx.x;
  int bg = bid >> 7, r = bid & 127, c = r >> 3, nc = r & 7;
  int g, k0, klen;
  if (c < 6)       { g = 0; k0 = c * 240;        klen = (c == 5)  ? 208 : 240; }
  else if (c < 10) { g = 1; k0 = (c - 6) * 224;  klen = 224; }
  else             { g = 2; k0 = (c - 10) * 240; klen = (c == 15) ? 208 : 240; }
  int s = (g == 0) ? (i - 1) : (g == 1 ? i : (i - 2));
  if (s < 0 || s >= NT) return;
  const float* Wg = (g == 0) ? P.w_rnn1 : (g == 1 ? P.w_att : P.w_rnn2);
  const float4* W4 = (const float4*)Wg;

  const float* p0 = P.corr + (size_t)s * NB * PREc;
  const float *p1, *p2, *p3;
  int s1, s2_, s3;
  if (g == 1) {  // za(s): [corr_s, aw(s-1), ah(s-1)]
    bool z = (s == 0);
    int pp = (s - 1) & 1;
    p1 = z ? P.zerob : P.aw + (size_t)pp * NB * 256; s1 = z ? 0 : 256;
    p2 = z ? P.zerob : P.ah + (size_t)pp * NB * DECc; s2_ = z ? 0 : DECc;
    p3 = P.zerob; s3 = 0;
  } else if (g == 0) {  // z1(s): [corr_s, aw(s), ah(s), h1(s-1)]
    int pp = s & 1;
    p1 = P.aw + (size_t)pp * NB * 256; s1 = 256;
    p2 = P.ah + (size_t)pp * NB * DECc; s2_ = DECc;
    bool z = (s == 0);
    p3 = z ? P.zerob : P.h1 + (size_t)((s - 1) & 1) * NB * DECc; s3 = z ? 0 : DECc;
  } else {  // z2(s): [corr_s, aw(s), h1(s), h2(s-1)]
    int pp = s & 1;
    p1 = P.aw + (size_t)pp * NB * 256; s1 = 256;
    p2 = P.h1 + (size_t)pp * NB * DECc; s2_ = DECc;
    bool z = (s == 0);
    p3 = z ? P.zerob : P.outs + (size_t)(s - 1) * NB * DECc; s3 = z ? 0 : DECc;
  }
  // stage x: kk = tid (coalesced global, conflict-free LDS)
  {
    int kk = tid;
    if (kk < klen) {
      int k = k0 + kk;
#pragma unroll 4
      for (int bi = 0; bi < 16; ++bi) {
        int b = bg * 16 + bi;
        float v;
        int kx = k;
        if (kx < PREc)
          v = p0[(size_t)b * PREc + kx];
        else {
          kx -= PREc;
          if (kx < 256)
            v = p1[(size_t)b * s1 + kx];
          else {
            kx -= 256;
            if (kx < DECc)
              v = p2[(size_t)b * s2_ + kx];
            else
              v = p3[(size_t)b * s3 + (kx - DECc)];
          }
        }
        xs[bi][kk] = v;
      }
    }
  }
  __syncthreads();
  float4 acc[4];
#pragma unroll
  for (int q = 0; q < 4; ++q) acc[q] = make_float4(0.f, 0.f, 0.f, 0.f);
  int bsub = tid >> 6, ct = tid & 63;
  const float4* Wp = W4 + (size_t)k0 * 512 + nc * 64 + ct;
  int kl4 = klen >> 2;
#pragma unroll 2
  for (int k4 = 0; k4 < kl4; ++k4) {
    float4 xv[4];
#pragma unroll
    for (int bi = 0; bi < 4; ++bi) xv[bi] = *(const float4*)&xs[bsub * 4 + bi][k4 * 4];
#pragma unroll
    for (int q = 0; q < 4; ++q) {
      float4 w = Wp[(size_t)(k4 * 4 + q) * 512];
#pragma unroll
      for (int bi = 0; bi < 4; ++bi) {
        float xq = (q == 0) ? xv[bi].x : (q == 1) ? xv[bi].y : (q == 2) ? xv[bi].z : xv[bi].w;
        acc[bi].x += w.x * xq;
        acc[bi].y += w.y * xq;
        acc[bi].z += w.z * xq;
        acc[bi].w += w.w * xq;
      }
    }
  }
  float4* zp = (float4*)(P.zX + ((size_t)c * NB + bg * 16 + bsub * 4) * 2048) + nc * 64 + ct;
#pragma unroll
  for (int bi = 0; bi < 4; ++bi) zp[(size_t)bi * 512] = acc[bi];
}

// ---------------- decoder phase B: gates + attention ----------------
struct DecBp {
  const float *mel_mask, *text_mask, *ctx, *zX;
  const float *b_att, *b_rnn1, *b_rnn2, *w_proj, *b_proj;
  float *aw, *ak, *ah, *ac, *h1, *c1, *c2, *outs;
};

__device__ __forceinline__ void do_gate(const float* zX, int clo, int chi, const float* bias,
                                        const float* cprev, const float* hprev, bool zfirst,
                                        const float* mm, float* hout, float* cout, int b, int j) {
  float2 zi = *(const float2*)(bias + j);
  float2 zf = *(const float2*)(bias + 512 + j);
  float2 zg = *(const float2*)(bias + 1024 + j);
  float2 zo = *(const float2*)(bias + 1536 + j);
  for (int c = clo; c <= chi; ++c) {
    const float* q = zX + ((size_t)c * NB + b) * 2048 + j;
    float2 a = *(const float2*)q;
    float2 f2 = *(const float2*)(q + 512);
    float2 g2 = *(const float2*)(q + 1024);
    float2 o2 = *(const float2*)(q + 1536);
    zi.x += a.x; zi.y += a.y;
    zf.x += f2.x; zf.y += f2.y;
    zg.x += g2.x; zg.y += g2.y;
    zo.x += o2.x; zo.y += o2.y;
  }
  float2 cp = zfirst ? make_float2(0.f, 0.f) : *(const float2*)(cprev + (size_t)b * 512 + j);
  float2 hp = zfirst ? make_float2(0.f, 0.f) : *(const float2*)(hprev + (size_t)b * 512 + j);
  float m = mm[b];
  float cnx = sigm(zf.x) * cp.x + sigm(zi.x) * tanhf(zg.x);
  float cny = sigm(zf.y) * cp.y + sigm(zi.y) * tanhf(zg.y);
  float hnx = sigm(zo.x) * tanhf(cnx);
  float hny = sigm(zo.y) * tanhf(cny);
  *(float2*)(hout + (size_t)b * 512 + j) =
      make_float2(m * hnx + (1.f - m) * hp.x, m * hny + (1.f - m) * hp.y);
  *(float2*)(cout + (size_t)b * 512 + j) =
      make_float2(m * cnx + (1.f - m) * cp.x, m * cny + (1.f - m) * cp.y);
}

__global__ __launch_bounds__(256) void k_decB(DecBp P, int i) {
  __shared__ float sh[1152];
  int tid = threadIdx.x, bid = blockIdx.x;
  if (bid < 64) {  // gate1, s = i-1
    int s = i - 1;
    if (s < 0 || s >= NT) return;
    bool z = (s == 0);
    do_gate(P.zX, 0, 5, P.b_rnn1,
            z ? P.zX : P.c1 + (size_t)((s - 1) & 1) * NB * 512,
            z ? P.zX : P.h1 + (size_t)((s - 1) & 1) * NB * 512, z,
            P.mel_mask + (size_t)s * NB,
            P.h1 + (size_t)(s & 1) * NB * 512,
            P.c1 + (size_t)(s & 1) * NB * 512, bid, 2 * tid);
    return;
  }
  if (bid < 128) {  // gate2, s = i-2
    int s = i - 2;
    if (s < 0 || s >= NT) return;
    bool z = (s == 0);
    do_gate(P.zX, 10, 15, P.b_rnn2,
            z ? P.zX : P.c2 + (size_t)((s - 1) & 1) * NB * 512,
            z ? P.zX : P.outs + (size_t)(s - 1) * NB * 512, z,
            P.mel_mask + (size_t)s * NB,
            P.outs + (size_t)s * NB * 512,
            P.c2 + (size_t)(s & 1) * NB * 512, bid - 64, 2 * tid);
    return;
  }
  // attention, s = i
  int s = i;
  if (s >= NT) return;
  int b = bid - 128;
  float* ah_s = sh;          // 512
  float* red_s = sh + 512;   // 256
  float* pr_s = sh + 768;    // 32
  float* abk = sh + 800;     // 96
  float* phi_s = sh + 896;   // 256
  float m = P.mel_mask[(size_t)s * NB + b];
  bool z = (s == 0);
  int pp = (s - 1) & 1;
  {
    int j = 2 * tid;
    float2 zi = *(const float2*)(P.b_att + j);
    float2 zf = *(const float2*)(P.b_att + 512 + j);
    float2 zg = *(const float2*)(P.b_att + 1024 + j);
    float2 zo = *(const float2*)(P.b_att + 1536 + j);
    for (int cc = 6; cc <= 9; ++cc) {
      const float* q = P.zX + ((size_t)cc * NB + b) * 2048 + j;
      float2 a = *(const float2*)q;
      float2 f2 = *(const float2*)(q + 512);
      float2 g2 = *(const float2*)(q + 1024);
      float2 o2 = *(const float2*)(q + 1536);
      zi.x += a.x; zi.y += a.y;
      zf.x += f2.x; zf.y += f2.y;
      zg.x += g2.x; zg.y += g2.y;
      zo.x += o2.x; zo.y += o2.y;
    }
    float2 cp = z ? make_float2(0.f, 0.f)
                  : *(const float2*)(P.ac + (size_t)pp * NB * 512 + (size_t)b * 512 + j);
    float2 hp = z ? make_float2(0.f, 0.f)
                  : *(const float2*)(P.ah + (size_t)pp * NB * 512 + (size_t)b * 512 + j);
    float cnx = sigm(zf.x) * cp.x + sigm(zi.x) * tanhf(zg.x);
    float cny = sigm(zf.y) * cp.y + sigm(zi.y) * tanhf(zg.y);
    float hrx = sigm(zo.x) * tanhf(cnx);
    float hry = sigm(zo.y) * tanhf(cny);
    ah_s[j] = hrx;
    ah_s[j + 1] = hry;
    *(float2*)(P.ah + (size_t)(s & 1) * NB * 512 + (size_t)b * 512 + j) =
        make_float2(m * hrx + (1.f - m) * hp.x, m * hry + (1.f - m) * hp.y);
    *(float2*)(P.ac + (size_t)(s & 1) * NB * 512 + (size_t)b * 512 + j) =
        make_float2(m * cnx + (1.f - m) * cp.x, m * cny + (1.f - m) * cp.y);
  }
  __syncthreads();
  {
    int cc2 = tid & 31, ch = tid >> 5;
    float ssum = 0.f;
    if (cc2 < 30)
      for (int k = ch * 64; k < ch * 64 + 64; ++k) ssum += ah_s[k] * P.w_proj[k * 30 + cc2];
    red_s[ch * 32 + cc2] = ssum;
  }
  __syncthreads();
  if (tid < 30) {
    float ssum = P.b_proj[tid];
    for (int ch = 0; ch < 8; ++ch) ssum += red_s[ch * 32 + tid];
    pr_s[tid] = ssum;
  }
  __syncthreads();
  if (tid < WMc) {
    float kp = z ? 0.f : P.ak[(size_t)pp * NB * AKS + (size_t)b * AKS + tid];
    float a_t = softplusf(pr_s[tid]);
    float b_t = softplusf(pr_s[WMc + tid]);
    float k_t = kp + softplusf(pr_s[2 * WMc + tid]);
    abk[tid] = a_t;
    abk[32 + tid] = b_t;
    abk[64 + tid] = k_t;
    P.ak[(size_t)(s & 1) * NB * AKS + (size_t)b * AKS + tid] = m * k_t + (1.f - m) * kp;
  }
  __syncthreads();
  {
    int u = tid;
    float ssum = 0.f;
#pragma unroll
    for (int gg = 0; gg < WMc; ++gg) {
      float dd = abk[64 + gg] - (float)u;
      ssum += abk[gg] * expf(-abk[32 + gg] * dd * dd);
    }
    phi_s[u] = ssum * P.text_mask[u * NB + b];
  }
  __syncthreads();
  {
    int dcol = tid;
    float ssum = 0.f;
#pragma unroll 8
    for (int u = 0; u < NU; ++u)
      ssum += phi_s[u] * __builtin_nontemporal_load(P.ctx + ((size_t)u * NB + b) * 256 + dcol);
    float wprev = z ? 0.f : P.aw[(size_t)pp * NB * 256 + (size_t)b * 256 + dcol];
    P.aw[(size_t)(s & 1) * NB * 256 + (size_t)b * 256 + dcol] = m * ssum + (1.f - m) * wprev;
  }
}

// =====================================================================================
extern "C" void kernel_launch(void* const* d_in, const int* in_sizes, int n_in,
                              void* d_out, int out_size, void* d_ws, size_t ws_size,
                              hipStream_t stream) {
  const float* in_mels = (const float*)d_in[0];
  const float* mel_mask = (const float*)d_in[1];
  const int* text = (const int*)d_in[2];
  const float* text_mask = (const float*)d_in[3];
  const float* w_pre1 = (const float*)d_in[4];
  const float* b_pre1 = (const float*)d_in[5];
  const float* w_pre2 = (const float*)d_in[6];
  const float* b_pre2 = (const float*)d_in[7];
  const float* emb = (const float*)d_in[8];
  const float* conv_w0 = (const float*)d_in[9];
  const float* conv_b0 = (const float*)d_in[10];
  const float* conv_w1 = (const float*)d_in[11];
  const float* conv_b1 = (const float*)d_in[12];
  const float* conv_w2 = (const float*)d_in[13];
  const float* conv_b2 = (const float*)d_in[14];
  const float* w_bif = (const float*)d_in[15];
  const float* b_bif = (const float*)d_in[16];
  const float* w_bib = (const float*)d_in[17];
  const float* b_bib = (const float*)d_in[18];
  const float* w_att = (const float*)d_in[19];
  const float* b_att = (const float*)d_in[20];
  const float* w_proj = (const float*)d_in[21];
  const float* b_proj = (const float*)d_in[22];
  const float* w_rnn1 = (const float*)d_in[23];
  const float* b_rnn1 = (const float*)d_in[24];
  const float* w_rnn2 = (const float*)d_in[25];
  const float* b_rnn2 = (const float*)d_in[26];
  const float* w_outp = (const float*)d_in[27];
  const float* b_outp = (const float*)d_in[28];

  float* ws = (float*)d_ws;
  size_t off = 0;
  auto alloc = [&](size_t n) {
    float* p = ws + off;
    off += (n + 63) & ~(size_t)63;
    return p;
  };
  float* corr = alloc((size_t)NT * NB * PREc);
  float* embx = alloc((size_t)NB * NU * EMBc);
  float* zX = alloc((size_t)16 * NB * 2048);       // decoder partials; also conv ping / prenet tmp
  float* ctx = alloc((size_t)NU * NB * 2 * ENCc);  // also conv pong
  float* zE = alloc((size_t)2 * 8 * NB * 512);
  float* hbufE = alloc((size_t)4 * NB * ENCc);
  float* cbufE = alloc((size_t)4 * NB * ENCc);
  float* aw = alloc((size_t)2 * NB * 2 * ENCc);
  float* ak = alloc((size_t)2 * NB * AKS);
  float* ah = alloc((size_t)2 * NB * DECc);
  float* ac = alloc((size_t)2 * NB * DECc);
  float* h1 = alloc((size_t)2 * NB * DECc);
  float* c1 = alloc((size_t)2 * NB * DECc);
  float* c2 = alloc((size_t)2 * NB * DECc);
  float* outs = alloc((size_t)NT * NB * DECc);  // h2 rows; front also conv output
  float* weff0 = alloc((size_t)5 * EMBc * NFc);
  float* beff0 = alloc(NFc);
  float* weff1 = alloc((size_t)5 * NFc * NFc);
  float* beff1 = alloc(NFc);
  float* weff2 = alloc((size_t)5 * NFc * NFc);
  float* beff2 = alloc(NFc);
  float* zerob = alloc(1024);

  float* convA = zX;
  float* convB = ctx;
  float* convOut = outs;
  float* tmp = zX;

  hipMemsetAsync(zerob, 0, 1024 * sizeof(float), stream);

  // ---- prenet ----
  k_dense<NMELc, PREc, 8><<<NT * NB / 8, 128, 0, stream>>>(in_mels, w_pre1, b_pre1, tmp, NT * NB);
  k_dense<PREc, PREc, 8><<<NT * NB / 8, 128, 0, stream>>>(tmp, w_pre2, b_pre2, corr, NT * NB);

  // ---- text conv stacks: embx -> convB -> convA -> convOut ----
  k_embed<<<(NB * NU * EMBc + 255) / 256, 256, 0, stream>>>(text, emb, embx);
  k_weff<EMBc><<<(5 * EMBc * NFc + 255) / 256, 256, 0, stream>>>(conv_w0, conv_b0, weff0, beff0);
  k_weff<NFc><<<(5 * NFc * NFc + 255) / 256, 256, 0, stream>>>(conv_w1, conv_b1, weff1, beff1);
  k_weff<NFc><<<(5 * NFc * NFc + 255) / 256, 256, 0, stream>>>(conv_w2, conv_b2, weff2, beff2);
  k_conv<EMBc, false><<<dim3(NU / 8, NB), 128, 0, stream>>>(embx, weff0, beff0, convB);
  k_conv<NFc, true><<<dim3(NU / 8, NB), 128, 0, stream>>>(convB, weff1, beff1, convA);
  k_conv<NFc, true><<<dim3(NU / 8, NB), 128, 0, stream>>>(convA, weff2, beff2, convOut);

  // ---- encoder BiLSTM (1 launch/step) ----
  for (int u = 0; u <= NU; ++u) {
    dim3 g(NB / 4, (u == NU) ? 1 : 4, 2);
    k_enc2<<<g, 128, 0, stream>>>(u, (u == NU) ? 1 : 0, w_bif, b_bif, w_bib, b_bib, convOut,
                                  text_mask, ctx, hbufE, cbufE, zE);
  }

  // ---- decoder: 2 launches per pipeline slot ----
  DecAp A;
  A.corr = corr; A.w_rnn1 = w_rnn1; A.w_att = w_att; A.w_rnn2 = w_rnn2;
  A.aw = aw; A.ah = ah; A.h1 = h1; A.outs = outs; A.zerob = zerob;
  A.zX = zX;
  DecBp Bp;
  Bp.mel_mask = mel_mask; Bp.text_mask = text_mask; Bp.ctx = ctx; Bp.zX = zX;
  Bp.b_att = b_att; Bp.b_rnn1 = b_rnn1; Bp.b_rnn2 = b_rnn2;
  Bp.w_proj = w_proj; Bp.b_proj = b_proj;
  Bp.aw = aw; Bp.ak = ak; Bp.ah = ah; Bp.ac = ac;
  Bp.h1 = h1; Bp.c1 = c1; Bp.c2 = c2; Bp.outs = outs;
  for (int i = 0; i <= NT + 1; ++i) {
    k_decA<<<512, 256, 0, stream>>>(A, i);
    k_decB<<<192, 256, 0, stream>>>(Bp, i);
  }

  // ---- output projection ----
  k_dense<DECc, NMELc, 8><<<NT * NB / 8, 128, 0, stream>>>(outs, w_outp, b_outp, (float*)d_out,
                                                           NT * NB);
}

// Round 11
// 13248.686 us; speedup vs baseline: 3.7934x; 1.3683x over previous
//
#include <hip/hip_runtime.h>
#include <math.h>

constexpr int NB    = 64;
constexpr int NT    = 256;
constexpr int NU    = 256;
constexpr int NMELc = 80;
constexpr int PREc  = 128;
constexpr int EMBc  = 15;
constexpr int NFc   = 128;
constexpr int ENCc  = 128;
constexpr int DECc  = 512;
constexpr int WMc   = 10;
constexpr int AKS   = 16;
constexpr size_t WSZ = (size_t)116 * 128 * 512;  // ushorts per weight plane (hi or lo)

using bf16x8 = __attribute__((ext_vector_type(8))) short;
using us8    = __attribute__((ext_vector_type(8))) unsigned short;
using f32x4  = __attribute__((ext_vector_type(4))) float;

__device__ __forceinline__ float sigm(float x) { return 1.0f / (1.0f + expf(-x)); }
__device__ __forceinline__ float softplusf(float x) { return fmaxf(x, 0.0f) + log1pf(expf(-fabsf(x))); }
__device__ __forceinline__ unsigned short f2bf(float f) {
  unsigned u = __builtin_bit_cast(unsigned, f);
  return (unsigned short)((u + 0x7FFFu + ((u >> 16) & 1u)) >> 16);
}
__device__ __forceinline__ float bf2f(unsigned short h) {
  return __builtin_bit_cast(float, (unsigned)h << 16);
}

// ---------------- generic dense ----------------
template <int K, int N, int RB>
__global__ void k_dense(const float* __restrict__ X, const float* __restrict__ W,
                        const float* __restrict__ bias, float* __restrict__ Y, int R) {
  __shared__ float xs[RB][K];
  int r0 = blockIdx.x * RB;
  int tid = threadIdx.x;  // 128
  for (int idx = tid; idx < RB * K; idx += 128) {
    int r = idx / K, k = idx % K;
    xs[r][k] = (r0 + r < R) ? X[(size_t)(r0 + r) * K + k] : 0.0f;
  }
  __syncthreads();
  int j = tid;
  if (j >= N) return;
  float acc[RB];
#pragma unroll
  for (int r = 0; r < RB; ++r) acc[r] = 0.f;
  for (int k = 0; k < K; ++k) {
    float w = W[(size_t)k * N + j];
#pragma unroll
    for (int r = 0; r < RB; ++r) acc[r] += xs[r][k] * w;
  }
  float bj = bias[j];
  for (int r = 0; r < RB; ++r)
    if (r0 + r < R) Y[(size_t)(r0 + r) * N + j] = acc[r] + bj;
}

// ---------------- embedding gather ----------------
__global__ void k_embed(const int* __restrict__ text, const float* __restrict__ emb,
                        float* __restrict__ out) {
  int idx = blockIdx.x * blockDim.x + threadIdx.x;
  if (idx >= NB * NU * EMBc) return;
  int c = idx % EMBc;
  int bu = idx / EMBc;
  int u = bu % NU, b = bu / NU;
  out[idx] = emb[text[u * NB + b] * EMBc + c];
}

// ---------------- merged conv weights ----------------
template <int CIN>
__global__ void k_weff(const float* __restrict__ w, const float* __restrict__ bb,
                       float* __restrict__ weff, float* __restrict__ beff) {
  int idx = blockIdx.x * blockDim.x + threadIdx.x;
  const int tot = 5 * CIN * NFc;
  if (idx < tot) {
    int f = idx % NFc;
    int tc = idx / NFc;
    int c = tc % CIN, t = tc / CIN;
    float m0 = (t == 2) ? 1.f : 0.f;
    float m1 = (t >= 1 && t <= 3) ? 1.f : 0.f;
    float w0 = w[((size_t)(0 * 5 + t) * CIN + c) * NFc + f];
    float w1 = w[((size_t)(1 * 5 + t) * CIN + c) * NFc + f];
    float w2 = w[((size_t)(2 * 5 + t) * CIN + c) * NFc + f];
    weff[idx] = w0 * m0 + w1 * m1 + w2;
  }
  if (idx < NFc) beff[idx] = bb[idx] + bb[NFc + idx] + bb[2 * NFc + idx];
}

// ---------------- conv stack ----------------
template <int CIN, bool RES>
__global__ void k_conv(const float* __restrict__ x, const float* __restrict__ weff,
                       const float* __restrict__ beff, float* __restrict__ y) {
  const int UT = 8;
  __shared__ float xs[(UT + 4) * CIN];
  int b = blockIdx.y, u0 = blockIdx.x * UT;
  int tid = threadIdx.x;  // 128
  for (int idx = tid; idx < (UT + 4) * CIN; idx += 128) {
    int c = idx % CIN;
    int uu = idx / CIN;
    int u = u0 + uu - 2;
    xs[idx] = (u >= 0 && u < NU) ? x[((size_t)b * NU + u) * CIN + c] : 0.f;
  }
  __syncthreads();
  int f = tid;
  float acc[UT];
#pragma unroll
  for (int r = 0; r < UT; ++r) acc[r] = beff[f];
  for (int t = 0; t < 5; ++t)
    for (int c = 0; c < CIN; ++c) {
      float w = weff[((size_t)t * CIN + c) * NFc + f];
#pragma unroll
      for (int r = 0; r < UT; ++r) acc[r] += xs[(r + t) * CIN + c] * w;
    }
  for (int r = 0; r < UT; ++r) {
    float v = fmaxf(acc[r], 0.f);
    if (RES) v += xs[(r + 2) * CIN + f];
    y[((size_t)b * NU + u0 + r) * NFc + f] = v;
  }
}

// ---------------- encoder BiLSTM fused step ----------------
__global__ __launch_bounds__(128) void k_enc2(int u, int gate_only,
                                              const float* __restrict__ Wf, const float* __restrict__ bf,
                                              const float* __restrict__ Wb, const float* __restrict__ bb_,
                                              const float* __restrict__ convt,
                                              const float* __restrict__ text_mask,
                                              float* __restrict__ ctx, float* __restrict__ hbuf,
                                              float* __restrict__ cbuf, float* __restrict__ zE) {
  const size_t ZPS = (size_t)8 * NB * 512;
  __shared__ float hs[4][128];
  __shared__ float xs[4][64];
  int tid = threadIdx.x;
  int g = blockIdx.x, q = blockIdx.y, d = blockIdx.z;
  int b0 = g * 4;
  const float* Wd = d ? Wb : Wf;
  const float* bd = d ? bb_ : bf;
  int j = tid;
  if (u > 0) {
    int ig = u - 1;
    int upos = d ? (NU - 1 - ig) : ig;
    const float* zr = zE + (size_t)((u - 1) & 1) * ZPS + (size_t)d * 4 * NB * 512;
    for (int bi = 0; bi < 4; ++bi) {
      int b = b0 + bi;
      float zi = bd[j], zf = bd[128 + j], zg = bd[256 + j], zo = bd[384 + j];
      for (int qq = 0; qq < 4; ++qq) {
        const float* p = zr + ((size_t)qq * NB + b) * 512;
        zi += p[j];
        zf += p[128 + j];
        zg += p[256 + j];
        zo += p[384 + j];
      }
      float cp = 0.f, hp = 0.f;
      if (u >= 2) {
        cp = cbuf[((size_t)(d * 2 + (u & 1)) * NB + b) * 128 + j];
        hp = hbuf[((size_t)(d * 2 + (u & 1)) * NB + b) * 128 + j];
      }
      float cn = sigm(zf) * cp + sigm(zi) * tanhf(zg);
      float hn = sigm(zo) * tanhf(cn);
      float mt = text_mask[upos * NB + b];
      hn = mt * hn + (1.f - mt) * hp;
      cn = mt * cn + (1.f - mt) * cp;
      hs[bi][j] = hn;
      if (q == 0) {
        hbuf[((size_t)(d * 2 + ((u - 1) & 1)) * NB + b) * 128 + j] = hn;
        cbuf[((size_t)(d * 2 + ((u - 1) & 1)) * NB + b) * 128 + j] = cn;
        ctx[((size_t)upos * NB + b) * 256 + d * 128 + j] = hn;
      }
    }
  } else {
#pragma unroll
    for (int bi = 0; bi < 4; ++bi) hs[bi][j] = 0.f;
  }
  if (gate_only) return;
  __syncthreads();
  int k0 = q * 64;
  {
    int upos_x = d ? (NU - 1 - u) : u;
    for (int idx = tid; idx < 4 * 64; idx += 128) {
      int bi = idx >> 6, kk = idx & 63;
      int k = k0 + kk;
      float v = (k < 128) ? convt[((size_t)(b0 + bi) * NU + upos_x) * 128 + k] : hs[bi][k - 128];
      xs[bi][kk] = v;
    }
  }
  __syncthreads();
  float4 acc[4];
#pragma unroll
  for (int bi = 0; bi < 4; ++bi) acc[bi] = make_float4(0.f, 0.f, 0.f, 0.f);
  const float4* Wp = (const float4*)Wd + (size_t)k0 * 128 + tid;
#pragma unroll 8
  for (int kk = 0; kk < 64; ++kk) {
    float4 w = Wp[(size_t)kk * 128];
#pragma unroll
    for (int bi = 0; bi < 4; ++bi) {
      float xv = xs[bi][kk];
      acc[bi].x += w.x * xv;
      acc[bi].y += w.y * xv;
      acc[bi].z += w.z * xv;
      acc[bi].w += w.w * xv;
    }
  }
  float4* zw = (float4*)(zE + (size_t)(u & 1) * ZPS) + ((size_t)(d * 4 + q) * NB + b0) * 128 + tid;
#pragma unroll
  for (int bi = 0; bi < 4; ++bi) zw[(size_t)bi * 128] = acc[bi];
}

// ---------------- weight prepack: fp32 W -> split bf16 (hi plane + lo plane), MFMA order ----
// Wpk_hi[((ktg*128+nt)*64+l)*8+j] = bf16(W[ktl*32+(l>>4)*8+j][nt*16+(l&15)]);
// Wpk_lo (at +WSZ) = bf16(residual). ktg: 0..43 w_rnn1, 44..71 w_att, 72..115 w_rnn2.
__global__ __launch_bounds__(256) void k_wcvt(const float* __restrict__ w1,
                                              const float* __restrict__ wa,
                                              const float* __restrict__ w2,
                                              unsigned short* __restrict__ Wpk) {
  int ktg = blockIdx.x;  // 0..115
  int ntg = blockIdx.y;  // 0..3
  const float* W;
  int ktl;
  if (ktg < 44) { W = w1; ktl = ktg; }
  else if (ktg < 72) { W = wa; ktl = ktg - 44; }
  else { W = w2; ktl = ktg - 72; }
  int tid = threadIdx.x;
  for (int p = 0; p < 8; ++p) {
    int idx = p * 256 + tid;  // ntl(32) x lane(64)
    int ntl = idx >> 6, l = idx & 63;
    int nt = ntg * 32 + ntl;
    us8 vh, vl;
#pragma unroll
    for (int j = 0; j < 8; ++j) {
      float wv = W[(size_t)(ktl * 32 + (l >> 4) * 8 + j) * 2048 + nt * 16 + (l & 15)];
      unsigned short h = f2bf(wv);
      vh[j] = h;
      vl[j] = f2bf(wv - bf2f(h));
    }
    size_t o = (((size_t)ktg * 128 + nt) * 64 + l) * 8;
    *(us8*)(Wpk + o) = vh;
    *(us8*)(Wpk + WSZ + o) = vl;
  }
}

// ---------------- decoder phase A: three GEMMs via split-bf16 MFMA ----------------
// Chunks (12): c 0..3 -> z1 (4 x 11 kt), c 4..7 -> za (4 x 7 kt), c 8..11 -> z2 (4 x 11 kt).
// Grid 384: bid = bg*96 + c*8 + nc. bg = 16 batches; nc = 256 cols (16 nt).
// A(i): za(i), z1(i-1), z2(i-2). zX layout [c][b][2048] fp32 partials.
// Split precision: x = xh + xl, W = Wh + Wl (bf16 each); z ~= xh*Wh + xl*Wh + xh*Wl.
struct DecAp {
  const float* corr;
  const unsigned short* Wpk;
  const float *aw, *ah, *h1, *outs, *zerob;
  float* zX;
};
__global__ __launch_bounds__(256) void k_decA(DecAp P, int i) {
  __shared__ unsigned short xsh[16][360];
  __shared__ unsigned short xsl[16][360];
  int tid = threadIdx.x, bid = blockIdx.x;
  int bg = bid / 96, r = bid % 96, c = r >> 3, nc = r & 7;
  int g, ktg0, nkt, k0;
  if (c < 4)      { g = 0; ktg0 = c * 11;            nkt = 11; k0 = c * 352; }
  else if (c < 8) { g = 1; ktg0 = 44 + (c - 4) * 7;  nkt = 7;  k0 = (c - 4) * 224; }
  else            { g = 2; ktg0 = 72 + (c - 8) * 11; nkt = 11; k0 = (c - 8) * 352; }
  int s = (g == 0) ? (i - 1) : (g == 1 ? i : (i - 2));
  if (s < 0 || s >= NT) return;

  const float* p0 = P.corr + (size_t)s * NB * PREc;
  const float *p1, *p2, *p3;
  int s1, s2_, s3;
  if (g == 1) {  // za(s): [corr_s, aw(s-1), ah(s-1)]
    bool z = (s == 0);
    int pp = (s - 1) & 1;
    p1 = z ? P.zerob : P.aw + (size_t)pp * NB * 256; s1 = z ? 0 : 256;
    p2 = z ? P.zerob : P.ah + (size_t)pp * NB * DECc; s2_ = z ? 0 : DECc;
    p3 = P.zerob; s3 = 0;
  } else if (g == 0) {  // z1(s): [corr_s, aw(s), ah(s), h1(s-1)]
    int pp = s & 1;
    p1 = P.aw + (size_t)pp * NB * 256; s1 = 256;
    p2 = P.ah + (size_t)pp * NB * DECc; s2_ = DECc;
    bool z = (s == 0);
    p3 = z ? P.zerob : P.h1 + (size_t)((s - 1) & 1) * NB * DECc; s3 = z ? 0 : DECc;
  } else {  // z2(s): [corr_s, aw(s), h1(s), h2(s-1)]
    int pp = s & 1;
    p1 = P.aw + (size_t)pp * NB * 256; s1 = 256;
    p2 = P.h1 + (size_t)pp * NB * DECc; s2_ = DECc;
    bool z = (s == 0);
    p3 = z ? P.zerob : P.outs + (size_t)(s - 1) * NB * DECc; s3 = z ? 0 : DECc;
  }
  int klen = nkt * 32;
  // stage x as split bf16: coalesced over k, one batch row per pass
  for (int idx = tid; idx < klen; idx += 256) {
    int k = k0 + idx;
#pragma unroll 4
    for (int bi = 0; bi < 16; ++bi) {
      int b = bg * 16 + bi;
      float v;
      int kx = k;
      if (kx < PREc)
        v = p0[(size_t)b * PREc + kx];
      else {
        kx -= PREc;
        if (kx < 256)
          v = p1[(size_t)b * s1 + kx];
        else {
          kx -= 256;
          if (kx < DECc)
            v = p2[(size_t)b * s2_ + kx];
          else
            v = p3[(size_t)b * s3 + (kx - DECc)];
        }
      }
      unsigned short h = f2bf(v);
      xsh[bi][idx] = h;
      xsl[bi][idx] = f2bf(v - bf2f(h));
    }
  }
  __syncthreads();
  int w = tid >> 6, lane = tid & 63;
  const unsigned short* wbh =
      P.Wpk + ((size_t)ktg0 * 128 + (size_t)(nc * 16 + w * 4)) * 512 + lane * 8;
  const unsigned short* wbl = wbh + WSZ;
  const unsigned short* xh = &xsh[lane & 15][(lane >> 4) * 8];
  const unsigned short* xl = &xsl[lane & 15][(lane >> 4) * 8];
  f32x4 acc0 = {0.f, 0.f, 0.f, 0.f}, acc1 = acc0, acc2 = acc0, acc3 = acc0;
  for (int kt = 0; kt < nkt; ++kt) {
    bf16x8 a_h = *(const bf16x8*)(xh + kt * 32);
    bf16x8 a_l = *(const bf16x8*)(xl + kt * 32);
    const unsigned short* wph = wbh + (size_t)kt * 65536;  // 128*512
    const unsigned short* wpl = wbl + (size_t)kt * 65536;
    bf16x8 b0h = *(const bf16x8*)(wph);
    bf16x8 b1h = *(const bf16x8*)(wph + 512);
    bf16x8 b2h = *(const bf16x8*)(wph + 1024);
    bf16x8 b3h = *(const bf16x8*)(wph + 1536);
    bf16x8 b0l = *(const bf16x8*)(wpl);
    bf16x8 b1l = *(const bf16x8*)(wpl + 512);
    bf16x8 b2l = *(const bf16x8*)(wpl + 1024);
    bf16x8 b3l = *(const bf16x8*)(wpl + 1536);
    acc0 = __builtin_amdgcn_mfma_f32_16x16x32_bf16(a_h, b0h, acc0, 0, 0, 0);
    acc1 = __builtin_amdgcn_mfma_f32_16x16x32_bf16(a_h, b1h, acc1, 0, 0, 0);
    acc2 = __builtin_amdgcn_mfma_f32_16x16x32_bf16(a_h, b2h, acc2, 0, 0, 0);
    acc3 = __builtin_amdgcn_mfma_f32_16x16x32_bf16(a_h, b3h, acc3, 0, 0, 0);
    acc0 = __builtin_amdgcn_mfma_f32_16x16x32_bf16(a_l, b0h, acc0, 0, 0, 0);
    acc1 = __builtin_amdgcn_mfma_f32_16x16x32_bf16(a_l, b1h, acc1, 0, 0, 0);
    acc2 = __builtin_amdgcn_mfma_f32_16x16x32_bf16(a_l, b2h, acc2, 0, 0, 0);
    acc3 = __builtin_amdgcn_mfma_f32_16x16x32_bf16(a_l, b3h, acc3, 0, 0, 0);
    acc0 = __builtin_amdgcn_mfma_f32_16x16x32_bf16(a_h, b0l, acc0, 0, 0, 0);
    acc1 = __builtin_amdgcn_mfma_f32_16x16x32_bf16(a_h, b1l, acc1, 0, 0, 0);
    acc2 = __builtin_amdgcn_mfma_f32_16x16x32_bf16(a_h, b2l, acc2, 0, 0, 0);
    acc3 = __builtin_amdgcn_mfma_f32_16x16x32_bf16(a_h, b3l, acc3, 0, 0, 0);
  }
  // store: D row=(lane>>4)*4+rr (batch), col=lane&15 (within nt)
  int brow = bg * 16 + (lane >> 4) * 4;
  float* zb = P.zX + ((size_t)c * NB + brow) * 2048 + nc * 256 + w * 64 + (lane & 15);
#pragma unroll
  for (int rr = 0; rr < 4; ++rr) zb[(size_t)rr * 2048 + 0] = acc0[rr];
#pragma unroll
  for (int rr = 0; rr < 4; ++rr) zb[(size_t)rr * 2048 + 16] = acc1[rr];
#pragma unroll
  for (int rr = 0; rr < 4; ++rr) zb[(size_t)rr * 2048 + 32] = acc2[rr];
#pragma unroll
  for (int rr = 0; rr < 4; ++rr) zb[(size_t)rr * 2048 + 48] = acc3[rr];
}

// ---------------- decoder phase B: gates + attention ----------------
struct DecBp {
  const float *mel_mask, *text_mask, *ctx, *zX;
  const float *b_att, *b_rnn1, *b_rnn2, *w_proj, *b_proj;
  float *aw, *ak, *ah, *ac, *h1, *c1, *c2, *outs;
};

__device__ __forceinline__ void do_gate(const float* zX, int clo, int chi, const float* bias,
                                        const float* cprev, const float* hprev, bool zfirst,
                                        const float* mm, float* hout, float* cout, int b, int j) {
  float2 zi = *(const float2*)(bias + j);
  float2 zf = *(const float2*)(bias + 512 + j);
  float2 zg = *(const float2*)(bias + 1024 + j);
  float2 zo = *(const float2*)(bias + 1536 + j);
  for (int c = clo; c <= chi; ++c) {
    const float* q = zX + ((size_t)c * NB + b) * 2048 + j;
    float2 a = *(const float2*)q;
    float2 f2 = *(const float2*)(q + 512);
    float2 g2 = *(const float2*)(q + 1024);
    float2 o2 = *(const float2*)(q + 1536);
    zi.x += a.x; zi.y += a.y;
    zf.x += f2.x; zf.y += f2.y;
    zg.x += g2.x; zg.y += g2.y;
    zo.x += o2.x; zo.y += o2.y;
  }
  float2 cp = zfirst ? make_float2(0.f, 0.f) : *(const float2*)(cprev + (size_t)b * 512 + j);
  float2 hp = zfirst ? make_float2(0.f, 0.f) : *(const float2*)(hprev + (size_t)b * 512 + j);
  float m = mm[b];
  float cnx = sigm(zf.x) * cp.x + sigm(zi.x) * tanhf(zg.x);
  float cny = sigm(zf.y) * cp.y + sigm(zi.y) * tanhf(zg.y);
  float hnx = sigm(zo.x) * tanhf(cnx);
  float hny = sigm(zo.y) * tanhf(cny);
  *(float2*)(hout + (size_t)b * 512 + j) =
      make_float2(m * hnx + (1.f - m) * hp.x, m * hny + (1.f - m) * hp.y);
  *(float2*)(cout + (size_t)b * 512 + j) =
      make_float2(m * cnx + (1.f - m) * cp.x, m * cny + (1.f - m) * cp.y);
}

__global__ __launch_bounds__(256) void k_decB(DecBp P, int i) {
  __shared__ float sh[1152];
  int tid = threadIdx.x, bid = blockIdx.x;
  if (bid < 64) {  // gate1, s = i-1
    int s = i - 1;
    if (s < 0 || s >= NT) return;
    bool z = (s == 0);
    do_gate(P.zX, 0, 3, P.b_rnn1,
            z ? P.zX : P.c1 + (size_t)((s - 1) & 1) * NB * 512,
            z ? P.zX : P.h1 + (size_t)((s - 1) & 1) * NB * 512, z,
            P.mel_mask + (size_t)s * NB,
            P.h1 + (size_t)(s & 1) * NB * 512,
            P.c1 + (size_t)(s & 1) * NB * 512, bid, 2 * tid);
    return;
  }
  if (bid < 128) {  // gate2, s = i-2
    int s = i - 2;
    if (s < 0 || s >= NT) return;
    bool z = (s == 0);
    do_gate(P.zX, 8, 11, P.b_rnn2,
            z ? P.zX : P.c2 + (size_t)((s - 1) & 1) * NB * 512,
            z ? P.zX : P.outs + (size_t)(s - 1) * NB * 512, z,
            P.mel_mask + (size_t)s * NB,
            P.outs + (size_t)s * NB * 512,
            P.c2 + (size_t)(s & 1) * NB * 512, bid - 64, 2 * tid);
    return;
  }
  // attention, s = i
  int s = i;
  if (s >= NT) return;
  int b = bid - 128;
  float* ah_s = sh;
  float* red_s = sh + 512;
  float* pr_s = sh + 768;
  float* abk = sh + 800;
  float* phi_s = sh + 896;
  float m = P.mel_mask[(size_t)s * NB + b];
  bool z = (s == 0);
  int pp = (s - 1) & 1;
  {
    int j = 2 * tid;
    float2 zi = *(const float2*)(P.b_att + j);
    float2 zf = *(const float2*)(P.b_att + 512 + j);
    float2 zg = *(const float2*)(P.b_att + 1024 + j);
    float2 zo = *(const float2*)(P.b_att + 1536 + j);
    for (int cc = 4; cc <= 7; ++cc) {
      const float* q = P.zX + ((size_t)cc * NB + b) * 2048 + j;
      float2 a = *(const float2*)q;
      float2 f2 = *(const float2*)(q + 512);
      float2 g2 = *(const float2*)(q + 1024);
      float2 o2 = *(const float2*)(q + 1536);
      zi.x += a.x; zi.y += a.y;
      zf.x += f2.x; zf.y += f2.y;
      zg.x += g2.x; zg.y += g2.y;
      zo.x += o2.x; zo.y += o2.y;
    }
    float2 cp = z ? make_float2(0.f, 0.f)
                  : *(const float2*)(P.ac + (size_t)pp * NB * 512 + (size_t)b * 512 + j);
    float2 hp = z ? make_float2(0.f, 0.f)
                  : *(const float2*)(P.ah + (size_t)pp * NB * 512 + (size_t)b * 512 + j);
    float cnx = sigm(zf.x) * cp.x + sigm(zi.x) * tanhf(zg.x);
    float cny = sigm(zf.y) * cp.y + sigm(zi.y) * tanhf(zg.y);
    float hrx = sigm(zo.x) * tanhf(cnx);
    float hry = sigm(zo.y) * tanhf(cny);
    ah_s[j] = hrx;
    ah_s[j + 1] = hry;
    *(float2*)(P.ah + (size_t)(s & 1) * NB * 512 + (size_t)b * 512 + j) =
        make_float2(m * hrx + (1.f - m) * hp.x, m * hry + (1.f - m) * hp.y);
    *(float2*)(P.ac + (size_t)(s & 1) * NB * 512 + (size_t)b * 512 + j) =
        make_float2(m * cnx + (1.f - m) * cp.x, m * cny + (1.f - m) * cp.y);
  }
  __syncthreads();
  {
    int cc2 = tid & 31, ch = tid >> 5;
    float ssum = 0.f;
    if (cc2 < 30)
      for (int k = ch * 64; k < ch * 64 + 64; ++k) ssum += ah_s[k] * P.w_proj[k * 30 + cc2];
    red_s[ch * 32 + cc2] = ssum;
  }
  __syncthreads();
  if (tid < 30) {
    float ssum = P.b_proj[tid];
    for (int ch = 0; ch < 8; ++ch) ssum += red_s[ch * 32 + tid];
    pr_s[tid] = ssum;
  }
  __syncthreads();
  if (tid < WMc) {
    float kp = z ? 0.f : P.ak[(size_t)pp * NB * AKS + (size_t)b * AKS + tid];
    float a_t = softplusf(pr_s[tid]);
    float b_t = softplusf(pr_s[WMc + tid]);
    float k_t = kp + softplusf(pr_s[2 * WMc + tid]);
    abk[tid] = a_t;
    abk[32 + tid] = b_t;
    abk[64 + tid] = k_t;
    P.ak[(size_t)(s & 1) * NB * AKS + (size_t)b * AKS + tid] = m * k_t + (1.f - m) * kp;
  }
  __syncthreads();
  {
    int u = tid;
    float ssum = 0.f;
#pragma unroll
    for (int gg = 0; gg < WMc; ++gg) {
      float dd = abk[64 + gg] - (float)u;
      ssum += abk[gg] * expf(-abk[32 + gg] * dd * dd);
    }
    phi_s[u] = ssum * P.text_mask[u * NB + b];
  }
  __syncthreads();
  {
    int dcol = tid;
    float ssum = 0.f;
#pragma unroll 8
    for (int u = 0; u < NU; ++u)
      ssum += phi_s[u] * __builtin_nontemporal_load(P.ctx + ((size_t)u * NB + b) * 256 + dcol);
    float wprev = z ? 0.f : P.aw[(size_t)pp * NB * 256 + (size_t)b * 256 + dcol];
    P.aw[(size_t)(s & 1) * NB * 256 + (size_t)b * 256 + dcol] = m * ssum + (1.f - m) * wprev;
  }
}

// =====================================================================================
extern "C" void kernel_launch(void* const* d_in, const int* in_sizes, int n_in,
                              void* d_out, int out_size, void* d_ws, size_t ws_size,
                              hipStream_t stream) {
  const float* in_mels = (const float*)d_in[0];
  const float* mel_mask = (const float*)d_in[1];
  const int* text = (const int*)d_in[2];
  const float* text_mask = (const float*)d_in[3];
  const float* w_pre1 = (const float*)d_in[4];
  const float* b_pre1 = (const float*)d_in[5];
  const float* w_pre2 = (const float*)d_in[6];
  const float* b_pre2 = (const float*)d_in[7];
  const float* emb = (const float*)d_in[8];
  const float* conv_w0 = (const float*)d_in[9];
  const float* conv_b0 = (const float*)d_in[10];
  const float* conv_w1 = (const float*)d_in[11];
  const float* conv_b1 = (const float*)d_in[12];
  const float* conv_w2 = (const float*)d_in[13];
  const float* conv_b2 = (const float*)d_in[14];
  const float* w_bif = (const float*)d_in[15];
  const float* b_bif = (const float*)d_in[16];
  const float* w_bib = (const float*)d_in[17];
  const float* b_bib = (const float*)d_in[18];
  const float* w_att = (const float*)d_in[19];
  const float* b_att = (const float*)d_in[20];
  const float* w_proj = (const float*)d_in[21];
  const float* b_proj = (const float*)d_in[22];
  const float* w_rnn1 = (const float*)d_in[23];
  const float* b_rnn1 = (const float*)d_in[24];
  const float* w_rnn2 = (const float*)d_in[25];
  const float* b_rnn2 = (const float*)d_in[26];
  const float* w_outp = (const float*)d_in[27];
  const float* b_outp = (const float*)d_in[28];

  float* ws = (float*)d_ws;
  size_t off = 0;
  auto alloc = [&](size_t n) {
    float* p = ws + off;
    off += (n + 63) & ~(size_t)63;
    return p;
  };
  float* corr = alloc((size_t)NT * NB * PREc);
  float* embx = alloc((size_t)NB * NU * EMBc);
  float* wpkR = alloc(WSZ);  // hi+lo planes = 2*WSZ ushorts = WSZ floats (30.4MB); also prenet tmp / conv ping
  float* zX = alloc((size_t)12 * NB * 2048);
  float* ctx = alloc((size_t)NU * NB * 2 * ENCc);  // also conv pong
  float* zE = alloc((size_t)2 * 8 * NB * 512);
  float* hbufE = alloc((size_t)4 * NB * ENCc);
  float* cbufE = alloc((size_t)4 * NB * ENCc);
  float* aw = alloc((size_t)2 * NB * 2 * ENCc);
  float* ak = alloc((size_t)2 * NB * AKS);
  float* ah = alloc((size_t)2 * NB * DECc);
  float* ac = alloc((size_t)2 * NB * DECc);
  float* h1 = alloc((size_t)2 * NB * DECc);
  float* c1 = alloc((size_t)2 * NB * DECc);
  float* c2 = alloc((size_t)2 * NB * DECc);
  float* outs = alloc((size_t)NT * NB * DECc);  // h2 rows; front also conv output
  float* weff0 = alloc((size_t)5 * EMBc * NFc);
  float* beff0 = alloc(NFc);
  float* weff1 = alloc((size_t)5 * NFc * NFc);
  float* beff1 = alloc(NFc);
  float* weff2 = alloc((size_t)5 * NFc * NFc);
  float* beff2 = alloc(NFc);
  float* zerob = alloc(1024);

  unsigned short* Wpk = (unsigned short*)wpkR;
  float* tmp = wpkR;     // prenet tmp (dead before conv1)
  float* convA = wpkR;   // conv ping (dead before k_wcvt)
  float* convB = ctx;    // conv pong (dead before encoder ctx writes)
  float* convOut = outs; // final conv; encoder input (dead before decoder outs writes)

  hipMemsetAsync(zerob, 0, 1024 * sizeof(float), stream);

  // ---- prenet ----
  k_dense<NMELc, PREc, 8><<<NT * NB / 8, 128, 0, stream>>>(in_mels, w_pre1, b_pre1, tmp, NT * NB);
  k_dense<PREc, PREc, 8><<<NT * NB / 8, 128, 0, stream>>>(tmp, w_pre2, b_pre2, corr, NT * NB);

  // ---- text conv stacks: embx -> convB -> convA -> convOut ----
  k_embed<<<(NB * NU * EMBc + 255) / 256, 256, 0, stream>>>(text, emb, embx);
  k_weff<EMBc><<<(5 * EMBc * NFc + 255) / 256, 256, 0, stream>>>(conv_w0, conv_b0, weff0, beff0);
  k_weff<NFc><<<(5 * NFc * NFc + 255) / 256, 256, 0, stream>>>(conv_w1, conv_b1, weff1, beff1);
  k_weff<NFc><<<(5 * NFc * NFc + 255) / 256, 256, 0, stream>>>(conv_w2, conv_b2, weff2, beff2);
  k_conv<EMBc, false><<<dim3(NU / 8, NB), 128, 0, stream>>>(embx, weff0, beff0, convB);
  k_conv<NFc, true><<<dim3(NU / 8, NB), 128, 0, stream>>>(convB, weff1, beff1, convA);
  k_conv<NFc, true><<<dim3(NU / 8, NB), 128, 0, stream>>>(convA, weff2, beff2, convOut);

  // ---- prepack decoder weights to split bf16 MFMA order (after conv frees wpkR) ----
  k_wcvt<<<dim3(116, 4), 256, 0, stream>>>(w_rnn1, w_att, w_rnn2, Wpk);

  // ---- encoder BiLSTM (1 launch/step) ----
  for (int u = 0; u <= NU; ++u) {
    dim3 g(NB / 4, (u == NU) ? 1 : 4, 2);
    k_enc2<<<g, 128, 0, stream>>>(u, (u == NU) ? 1 : 0, w_bif, b_bif, w_bib, b_bib, convOut,
                                  text_mask, ctx, hbufE, cbufE, zE);
  }

  // ---- decoder: 2 launches per pipeline slot ----
  DecAp A;
  A.corr = corr; A.Wpk = Wpk;
  A.aw = aw; A.ah = ah; A.h1 = h1; A.outs = outs; A.zerob = zerob;
  A.zX = zX;
  DecBp Bp;
  Bp.mel_mask = mel_mask; Bp.text_mask = text_mask; Bp.ctx = ctx; Bp.zX = zX;
  Bp.b_att = b_att; Bp.b_rnn1 = b_rnn1; Bp.b_rnn2 = b_rnn2;
  Bp.w_proj = w_proj; Bp.b_proj = b_proj;
  Bp.aw = aw; Bp.ak = ak; Bp.ah = ah; Bp.ac = ac;
  Bp.h1 = h1; Bp.c1 = c1; Bp.c2 = c2; Bp.outs = outs;
  for (int i = 0; i <= NT + 1; ++i) {
    k_decA<<<384, 256, 0, stream>>>(A, i);
    k_decB<<<192, 256, 0, stream>>>(Bp, i);
  }

  // ---- output projection ----
  k_dense<DECc, NMELc, 8><<<NT * NB / 8, 128, 0, stream>>>(outs, w_outp, b_outp, (float*)d_out,
                                                           NT * NB);
}

// Round 12
// 13046.364 us; speedup vs baseline: 3.8522x; 1.0155x over previous
//
#include <hip/hip_runtime.h>
#include <math.h>

constexpr int NB    = 64;
constexpr int NT    = 256;
constexpr int NU    = 256;
constexpr int NMELc = 80;
constexpr int PREc  = 128;
constexpr int EMBc  = 15;
constexpr int NFc   = 128;
constexpr int ENCc  = 128;
constexpr int DECc  = 512;
constexpr int WMc   = 10;
constexpr int AKS   = 16;
constexpr size_t WSZ = (size_t)116 * 128 * 512;  // ushorts per weight plane (hi or lo)

using bf16x8 = __attribute__((ext_vector_type(8))) short;
using us8    = __attribute__((ext_vector_type(8))) unsigned short;
using f32x4  = __attribute__((ext_vector_type(4))) float;

__device__ __forceinline__ float sigm(float x) { return 1.0f / (1.0f + expf(-x)); }
__device__ __forceinline__ float softplusf(float x) { return fmaxf(x, 0.0f) + log1pf(expf(-fabsf(x))); }
__device__ __forceinline__ unsigned short f2bf(float f) {
  unsigned u = __builtin_bit_cast(unsigned, f);
  return (unsigned short)((u + 0x7FFFu + ((u >> 16) & 1u)) >> 16);
}
__device__ __forceinline__ float bf2f(unsigned short h) {
  return __builtin_bit_cast(float, (unsigned)h << 16);
}
// agent-relaxed bypass accessors (cross-XCD visible at L3, no cache maintenance)
__device__ __forceinline__ float ldF(const float* p) {
  return __hip_atomic_load(p, __ATOMIC_RELAXED, __HIP_MEMORY_SCOPE_AGENT);
}
__device__ __forceinline__ void stF(float* p, float v) {
  __hip_atomic_store(p, v, __ATOMIC_RELAXED, __HIP_MEMORY_SCOPE_AGENT);
}
__device__ __forceinline__ float2 ldF2(const float* p) {
  unsigned long long u = __hip_atomic_load((const unsigned long long*)p, __ATOMIC_RELAXED,
                                           __HIP_MEMORY_SCOPE_AGENT);
  return __builtin_bit_cast(float2, u);
}
__device__ __forceinline__ unsigned ldU(const unsigned* p) {
  return __hip_atomic_load(p, __ATOMIC_RELAXED, __HIP_MEMORY_SCOPE_AGENT);
}
__device__ __forceinline__ void stU(unsigned* p, unsigned v) {
  __hip_atomic_store(p, v, __ATOMIC_RELAXED, __HIP_MEMORY_SCOPE_AGENT);
}

// ---------------- generic dense ----------------
template <int K, int N, int RB>
__global__ void k_dense(const float* __restrict__ X, const float* __restrict__ W,
                        const float* __restrict__ bias, float* __restrict__ Y, int R) {
  __shared__ float xs[RB][K];
  int r0 = blockIdx.x * RB;
  int tid = threadIdx.x;  // 128
  for (int idx = tid; idx < RB * K; idx += 128) {
    int r = idx / K, k = idx % K;
    xs[r][k] = (r0 + r < R) ? X[(size_t)(r0 + r) * K + k] : 0.0f;
  }
  __syncthreads();
  int j = tid;
  if (j >= N) return;
  float acc[RB];
#pragma unroll
  for (int r = 0; r < RB; ++r) acc[r] = 0.f;
  for (int k = 0; k < K; ++k) {
    float w = W[(size_t)k * N + j];
#pragma unroll
    for (int r = 0; r < RB; ++r) acc[r] += xs[r][k] * w;
  }
  float bj = bias[j];
  for (int r = 0; r < RB; ++r)
    if (r0 + r < R) Y[(size_t)(r0 + r) * N + j] = acc[r] + bj;
}

// ---------------- embedding gather ----------------
__global__ void k_embed(const int* __restrict__ text, const float* __restrict__ emb,
                        float* __restrict__ out) {
  int idx = blockIdx.x * blockDim.x + threadIdx.x;
  if (idx >= NB * NU * EMBc) return;
  int c = idx % EMBc;
  int bu = idx / EMBc;
  int u = bu % NU, b = bu / NU;
  out[idx] = emb[text[u * NB + b] * EMBc + c];
}

// ---------------- merged conv weights ----------------
template <int CIN>
__global__ void k_weff(const float* __restrict__ w, const float* __restrict__ bb,
                       float* __restrict__ weff, float* __restrict__ beff) {
  int idx = blockIdx.x * blockDim.x + threadIdx.x;
  const int tot = 5 * CIN * NFc;
  if (idx < tot) {
    int f = idx % NFc;
    int tc = idx / NFc;
    int c = tc % CIN, t = tc / CIN;
    float m0 = (t == 2) ? 1.f : 0.f;
    float m1 = (t >= 1 && t <= 3) ? 1.f : 0.f;
    float w0 = w[((size_t)(0 * 5 + t) * CIN + c) * NFc + f];
    float w1 = w[((size_t)(1 * 5 + t) * CIN + c) * NFc + f];
    float w2 = w[((size_t)(2 * 5 + t) * CIN + c) * NFc + f];
    weff[idx] = w0 * m0 + w1 * m1 + w2;
  }
  if (idx < NFc) beff[idx] = bb[idx] + bb[NFc + idx] + bb[2 * NFc + idx];
}

// ---------------- conv stack ----------------
template <int CIN, bool RES>
__global__ void k_conv(const float* __restrict__ x, const float* __restrict__ weff,
                       const float* __restrict__ beff, float* __restrict__ y) {
  const int UT = 8;
  __shared__ float xs[(UT + 4) * CIN];
  int b = blockIdx.y, u0 = blockIdx.x * UT;
  int tid = threadIdx.x;  // 128
  for (int idx = tid; idx < (UT + 4) * CIN; idx += 128) {
    int c = idx % CIN;
    int uu = idx / CIN;
    int u = u0 + uu - 2;
    xs[idx] = (u >= 0 && u < NU) ? x[((size_t)b * NU + u) * CIN + c] : 0.f;
  }
  __syncthreads();
  int f = tid;
  float acc[UT];
#pragma unroll
  for (int r = 0; r < UT; ++r) acc[r] = beff[f];
  for (int t = 0; t < 5; ++t)
    for (int c = 0; c < CIN; ++c) {
      float w = weff[((size_t)t * CIN + c) * NFc + f];
#pragma unroll
      for (int r = 0; r < UT; ++r) acc[r] += xs[(r + t) * CIN + c] * w;
    }
  for (int r = 0; r < UT; ++r) {
    float v = fmaxf(acc[r], 0.f);
    if (RES) v += xs[(r + 2) * CIN + f];
    y[((size_t)b * NU + u0 + r) * NFc + f] = v;
  }
}

// ---------------- encoder x-part precompute: zx[d][u][b][512] = conv @ Wx + bias (fp16) ----
__global__ __launch_bounds__(512) void k_zx(const float* __restrict__ Wf,
                                            const float* __restrict__ bf,
                                            const float* __restrict__ Wb,
                                            const float* __restrict__ bb_,
                                            const float* __restrict__ convt,
                                            _Float16* __restrict__ zx) {
  __shared__ float xs[8][128];
  int du = blockIdx.x;
  int d = du >> 8, u = du & 255;
  int bg = blockIdx.y;  // 8 batches
  const float* Wd = d ? Wb : Wf;
  const float* bd = d ? bb_ : bf;
  int upos_x = d ? (NU - 1 - u) : u;
  int tid = threadIdx.x;
  for (int idx = tid; idx < 8 * 128; idx += 512) {
    int bi = idx >> 7, k = idx & 127;
    xs[bi][k] = convt[((size_t)(bg * 8 + bi) * NU + upos_x) * 128 + k];
  }
  __syncthreads();
  int j = tid;  // 512 cols
  float acc[8];
#pragma unroll
  for (int r = 0; r < 8; ++r) acc[r] = 0.f;
  for (int k = 0; k < 128; ++k) {
    float w = Wd[(size_t)k * 512 + j];
#pragma unroll
    for (int r = 0; r < 8; ++r) acc[r] += xs[r][k] * w;
  }
  float bj = bd[j];
#pragma unroll
  for (int r = 0; r < 8; ++r)
    zx[(((size_t)d * 256 + u) * 64 + bg * 8 + r) * 512 + j] = (_Float16)(acc[r] + bj);
}

// ---------------- persistent encoder: 32 blocks (g16 x d2), block-local chains ----------------
__global__ __launch_bounds__(256) void k_encP2(const float* __restrict__ Wf,
                                               const float* __restrict__ Wb,
                                               const _Float16* __restrict__ zx,
                                               const float* __restrict__ text_mask,
                                               float* __restrict__ ctx) {
  __shared__ float hs[4][128];
  __shared__ float zs[4][512];
  int bid = blockIdx.x;
  int d = bid & 1, g = bid >> 1;
  int b0 = g * 4;
  const float* Wh = (d ? Wb : Wf) + (size_t)128 * 512;  // h-part rows
  int tid = threadIdx.x;
  int q = tid >> 6, lane = tid & 63;
  int col0 = q * 128 + 2 * lane;
  float creg[2] = {0.f, 0.f};
  for (int idx = tid; idx < 512; idx += 256) hs[idx >> 7][idx & 127] = 0.f;
  __syncthreads();
  for (int u = 0; u < NU; ++u) {
    const _Float16* zxu = zx + (((size_t)d * 256 + u) * 64 + b0) * 512;
#pragma unroll
    for (int p = 0; p < 8; ++p) {
      int idx = p * 256 + tid;
      int bi = idx >> 9, cc = idx & 511;
      zs[bi][cc] = (float)zxu[(size_t)bi * 512 + cc];
    }
    __syncthreads();
    if (u > 0) {
      float2 acc[4];
#pragma unroll
      for (int bi = 0; bi < 4; ++bi) acc[bi] = make_float2(0.f, 0.f);
#pragma unroll 4
      for (int kk = 0; kk < 128; ++kk) {
        float2 w = *(const float2*)&Wh[(size_t)kk * 512 + col0];
#pragma unroll
        for (int bi = 0; bi < 4; ++bi) {
          float h = hs[bi][kk];
          acc[bi].x += w.x * h;
          acc[bi].y += w.y * h;
        }
      }
#pragma unroll
      for (int bi = 0; bi < 4; ++bi) {
        zs[bi][col0] += acc[bi].x;
        zs[bi][col0 + 1] += acc[bi].y;
      }
      __syncthreads();
    }
    int upos = d ? (NU - 1 - u) : u;
#pragma unroll
    for (int e = 0; e < 2; ++e) {
      int idx = 2 * tid + e;
      int bi = idx >> 7, j = idx & 127;
      int b = b0 + bi;
      float zi = zs[bi][j], zf = zs[bi][128 + j], zg = zs[bi][256 + j], zo = zs[bi][384 + j];
      float cp = creg[e], hp = hs[bi][j];
      float cn = sigm(zf) * cp + sigm(zi) * tanhf(zg);
      float hn = sigm(zo) * tanhf(cn);
      float mt = text_mask[upos * NB + b];
      hn = mt * hn + (1.f - mt) * hp;
      cn = mt * cn + (1.f - mt) * cp;
      creg[e] = cn;
      hs[bi][j] = hn;
      ctx[((size_t)upos * NB + b) * 256 + d * 128 + j] = hn;
    }
    __syncthreads();
  }
}

// ---------------- weight prepack: fp32 W -> split bf16 (hi+lo planes), MFMA order ----------------
__global__ __launch_bounds__(256) void k_wcvt(const float* __restrict__ w1,
                                              const float* __restrict__ wa,
                                              const float* __restrict__ w2,
                                              unsigned short* __restrict__ Wpk) {
  int ktg = blockIdx.x;  // 0..115
  int ntg = blockIdx.y;  // 0..3
  const float* W;
  int ktl;
  if (ktg < 44) { W = w1; ktl = ktg; }
  else if (ktg < 72) { W = wa; ktl = ktg - 44; }
  else { W = w2; ktl = ktg - 72; }
  int tid = threadIdx.x;
  for (int p = 0; p < 8; ++p) {
    int idx = p * 256 + tid;  // ntl(32) x lane(64)
    int ntl = idx >> 6, l = idx & 63;
    int nt = ntg * 32 + ntl;
    us8 vh, vl;
#pragma unroll
    for (int j = 0; j < 8; ++j) {
      float wv = W[(size_t)(ktl * 32 + (l >> 4) * 8 + j) * 2048 + nt * 16 + (l & 15)];
      unsigned short h = f2bf(wv);
      vh[j] = h;
      vl[j] = f2bf(wv - bf2f(h));
    }
    size_t o = (((size_t)ktg * 128 + nt) * 64 + l) * 8;
    *(us8*)(Wpk + o) = vh;
    *(us8*)(Wpk + WSZ + o) = vl;
  }
}

// ---------------- merged decoder step: A (3 GEMMs) + B (gates+att) in ONE launch ----------------
// A: 384 blocks: bg = bid/192 (32 batches), r = bid%192, c = r/16, nc = r%16 (128 cols).
//    chunks: c 0..3 z1(i-1) [ktg0=c*11], c 4..7 za(i) [44+(c-4)*7], c 8..11 z2(i-2) [72+(c-8)*11].
//    zX[c][b][2048] written via agent-bypass stores; flag[bid] = i+1 after syncthreads drain.
// B: 192 blocks (bid >= 384): 64 gate1(i-1) [polls flags c0..3], 64 gate2(i-2) [c8..11],
//    64 att(i) [c4..7]; zX read via agent-bypass loads.
struct DecMp {
  const float* corr;
  const unsigned short* Wpk;
  const float *mel_mask, *text_mask, *ctx;
  const float *b_att, *b_rnn1, *b_rnn2, *w_proj, *b_proj;
  float *aw, *ak, *ah, *ac, *h1, *c1, *c2, *outs, *zerob;
  float* zX;
  unsigned* flags;
};

__device__ __forceinline__ void wait_flags(const unsigned* flags, int base, unsigned target) {
  int tid = threadIdx.x;
  for (;;) {
    bool ok = true;
    if (tid < 128) {
      int f = (tid < 64) ? (base + tid) : (192 + base + (tid - 64));
      ok = (ldU(&flags[f]) >= target);
    }
    if (__syncthreads_and(ok)) break;
    __builtin_amdgcn_s_sleep(8);
  }
}

__device__ __forceinline__ void do_gateM(const float* zX, int clo, int chi, const float* bias,
                                         const float* cprev, const float* hprev, bool zfirst,
                                         const float* mm, float* hout, float* cout, int b, int j) {
  float2 zi = *(const float2*)(bias + j);
  float2 zf = *(const float2*)(bias + 512 + j);
  float2 zg = *(const float2*)(bias + 1024 + j);
  float2 zo = *(const float2*)(bias + 1536 + j);
  for (int c = clo; c <= chi; ++c) {
    const float* q = zX + ((size_t)c * NB + b) * 2048 + j;
    float2 a = ldF2(q), f2 = ldF2(q + 512), g2 = ldF2(q + 1024), o2 = ldF2(q + 1536);
    zi.x += a.x; zi.y += a.y;
    zf.x += f2.x; zf.y += f2.y;
    zg.x += g2.x; zg.y += g2.y;
    zo.x += o2.x; zo.y += o2.y;
  }
  float2 cp = zfirst ? make_float2(0.f, 0.f) : *(const float2*)(cprev + (size_t)b * 512 + j);
  float2 hp = zfirst ? make_float2(0.f, 0.f) : *(const float2*)(hprev + (size_t)b * 512 + j);
  float m = mm[b];
  float cnx = sigm(zf.x) * cp.x + sigm(zi.x) * tanhf(zg.x);
  float cny = sigm(zf.y) * cp.y + sigm(zi.y) * tanhf(zg.y);
  float hnx = sigm(zo.x) * tanhf(cnx);
  float hny = sigm(zo.y) * tanhf(cny);
  *(float2*)(hout + (size_t)b * 512 + j) =
      make_float2(m * hnx + (1.f - m) * hp.x, m * hny + (1.f - m) * hp.y);
  *(float2*)(cout + (size_t)b * 512 + j) =
      make_float2(m * cnx + (1.f - m) * cp.x, m * cny + (1.f - m) * cp.y);
}

__global__ __launch_bounds__(256) void k_decM(DecMp P, int i) {
  __shared__ __align__(16) unsigned short xsh[32][360];
  __shared__ __align__(16) unsigned short xsl[32][360];
  int tid = threadIdx.x, bid = blockIdx.x;
  if (bid < 384) {
    // ================= A part =================
    int bg = bid / 192, r = bid % 192, c = r >> 4, nc = r & 15;
    int g, ktg0, nkt, k0;
    if (c < 4)      { g = 0; ktg0 = c * 11;            nkt = 11; k0 = c * 352; }
    else if (c < 8) { g = 1; ktg0 = 44 + (c - 4) * 7;  nkt = 7;  k0 = (c - 4) * 224; }
    else            { g = 2; ktg0 = 72 + (c - 8) * 11; nkt = 11; k0 = (c - 8) * 352; }
    int s = (g == 0) ? (i - 1) : (g == 1 ? i : (i - 2));
    if (s >= 0 && s < NT) {
      const float* p0 = P.corr + (size_t)s * NB * PREc;
      const float *p1, *p2, *p3;
      int s1, s2_, s3;
      if (g == 1) {
        bool z = (s == 0);
        int pp = (s - 1) & 1;
        p1 = z ? P.zerob : P.aw + (size_t)pp * NB * 256; s1 = z ? 0 : 256;
        p2 = z ? P.zerob : P.ah + (size_t)pp * NB * DECc; s2_ = z ? 0 : DECc;
        p3 = P.zerob; s3 = 0;
      } else if (g == 0) {
        int pp = s & 1;
        p1 = P.aw + (size_t)pp * NB * 256; s1 = 256;
        p2 = P.ah + (size_t)pp * NB * DECc; s2_ = DECc;
        bool z = (s == 0);
        p3 = z ? P.zerob : P.h1 + (size_t)((s - 1) & 1) * NB * DECc; s3 = z ? 0 : DECc;
      } else {
        int pp = s & 1;
        p1 = P.aw + (size_t)pp * NB * 256; s1 = 256;
        p2 = P.h1 + (size_t)pp * NB * DECc; s2_ = DECc;
        bool z = (s == 0);
        p3 = z ? P.zerob : P.outs + (size_t)(s - 1) * NB * DECc; s3 = z ? 0 : DECc;
      }
      int klen = nkt * 32;
      for (int idx = tid; idx < klen; idx += 256) {
        int k = k0 + idx;
#pragma unroll 4
        for (int bi = 0; bi < 32; ++bi) {
          int b = bg * 32 + bi;
          float v;
          int kx = k;
          if (kx < PREc)
            v = p0[(size_t)b * PREc + kx];
          else {
            kx -= PREc;
            if (kx < 256)
              v = p1[(size_t)b * s1 + kx];
            else {
              kx -= 256;
              if (kx < DECc)
                v = p2[(size_t)b * s2_ + kx];
              else
                v = p3[(size_t)b * s3 + (kx - DECc)];
            }
          }
          unsigned short h = f2bf(v);
          xsh[bi][idx] = h;
          xsl[bi][idx] = f2bf(v - bf2f(h));
        }
      }
      __syncthreads();
      int w = tid >> 6, lane = tid & 63;
      const unsigned short* wb0 =
          P.Wpk + (((size_t)ktg0 * 128 + (size_t)(nc * 8 + w * 2)) * 64 + lane) * 8;
      f32x4 acc[2][2];
#pragma unroll
      for (int m = 0; m < 2; ++m)
#pragma unroll
        for (int t = 0; t < 2; ++t) acc[m][t] = f32x4{0.f, 0.f, 0.f, 0.f};
      int arow0 = lane & 15, acol = (lane >> 4) * 8;
      for (int kt = 0; kt < nkt; ++kt) {
        bf16x8 ah0 = *(const bf16x8*)&xsh[arow0][kt * 32 + acol];
        bf16x8 ah1 = *(const bf16x8*)&xsh[16 + arow0][kt * 32 + acol];
        bf16x8 al0 = *(const bf16x8*)&xsl[arow0][kt * 32 + acol];
        bf16x8 al1 = *(const bf16x8*)&xsl[16 + arow0][kt * 32 + acol];
        const unsigned short* wp = wb0 + (size_t)kt * 65536;
        bf16x8 b0h = *(const bf16x8*)(wp);
        bf16x8 b1h = *(const bf16x8*)(wp + 512);
        bf16x8 b0l = *(const bf16x8*)(wp + WSZ);
        bf16x8 b1l = *(const bf16x8*)(wp + WSZ + 512);
        acc[0][0] = __builtin_amdgcn_mfma_f32_16x16x32_bf16(ah0, b0h, acc[0][0], 0, 0, 0);
        acc[0][1] = __builtin_amdgcn_mfma_f32_16x16x32_bf16(ah0, b1h, acc[0][1], 0, 0, 0);
        acc[1][0] = __builtin_amdgcn_mfma_f32_16x16x32_bf16(ah1, b0h, acc[1][0], 0, 0, 0);
        acc[1][1] = __builtin_amdgcn_mfma_f32_16x16x32_bf16(ah1, b1h, acc[1][1], 0, 0, 0);
        acc[0][0] = __builtin_amdgcn_mfma_f32_16x16x32_bf16(al0, b0h, acc[0][0], 0, 0, 0);
        acc[0][1] = __builtin_amdgcn_mfma_f32_16x16x32_bf16(al0, b1h, acc[0][1], 0, 0, 0);
        acc[1][0] = __builtin_amdgcn_mfma_f32_16x16x32_bf16(al1, b0h, acc[1][0], 0, 0, 0);
        acc[1][1] = __builtin_amdgcn_mfma_f32_16x16x32_bf16(al1, b1h, acc[1][1], 0, 0, 0);
        acc[0][0] = __builtin_amdgcn_mfma_f32_16x16x32_bf16(ah0, b0l, acc[0][0], 0, 0, 0);
        acc[0][1] = __builtin_amdgcn_mfma_f32_16x16x32_bf16(ah0, b1l, acc[0][1], 0, 0, 0);
        acc[1][0] = __builtin_amdgcn_mfma_f32_16x16x32_bf16(ah1, b0l, acc[1][0], 0, 0, 0);
        acc[1][1] = __builtin_amdgcn_mfma_f32_16x16x32_bf16(ah1, b1l, acc[1][1], 0, 0, 0);
      }
#pragma unroll
      for (int m = 0; m < 2; ++m)
#pragma unroll
        for (int t = 0; t < 2; ++t) {
          int brow = bg * 32 + m * 16 + (lane >> 4) * 4;
          int col = nc * 128 + (w * 2 + t) * 16 + (lane & 15);
          float* zb = P.zX + ((size_t)c * NB + brow) * 2048 + col;
#pragma unroll
          for (int rr = 0; rr < 4; ++rr) stF(zb + (size_t)rr * 2048, acc[m][t][rr]);
        }
    }
    __syncthreads();  // drains vmcnt across all waves -> zX visible at L3
    if (tid == 0) stU(&P.flags[bid], (unsigned)(i + 1));
    return;
  }
  // ================= B part =================
  int wb = bid - 384;
  unsigned target = (unsigned)(i + 1);
  if (wb < 64) {  // gate1, s = i-1, consumes c 0..3
    int s = i - 1;
    if (s < 0 || s >= NT) return;
    wait_flags(P.flags, 0, target);
    bool z = (s == 0);
    do_gateM(P.zX, 0, 3, P.b_rnn1,
             z ? P.zerob : P.c1 + (size_t)((s - 1) & 1) * NB * 512,
             z ? P.zerob : P.h1 + (size_t)((s - 1) & 1) * NB * 512, z,
             P.mel_mask + (size_t)s * NB,
             P.h1 + (size_t)(s & 1) * NB * 512,
             P.c1 + (size_t)(s & 1) * NB * 512, wb, 2 * tid);
    return;
  }
  if (wb < 128) {  // gate2, s = i-2, consumes c 8..11
    int s = i - 2;
    if (s < 0 || s >= NT) return;
    wait_flags(P.flags, 128, target);
    bool z = (s == 0);
    do_gateM(P.zX, 8, 11, P.b_rnn2,
             z ? P.zerob : P.c2 + (size_t)((s - 1) & 1) * NB * 512,
             z ? P.zerob : P.outs + (size_t)(s - 1) * NB * 512, z,
             P.mel_mask + (size_t)s * NB,
             P.outs + (size_t)s * NB * 512,
             P.c2 + (size_t)(s & 1) * NB * 512, wb - 64, 2 * tid);
    return;
  }
  // attention, s = i, consumes c 4..7
  int s = i;
  if (s >= NT) return;
  wait_flags(P.flags, 64, target);
  int b = wb - 128;
  float* sh = (float*)&xsh[0][0];
  float* ah_s = sh;
  float* red_s = sh + 512;
  float* pr_s = sh + 768;
  float* abk = sh + 800;
  float* phi_s = sh + 896;
  float m = P.mel_mask[(size_t)s * NB + b];
  bool z = (s == 0);
  int pp = (s - 1) & 1;
  {
    int j = 2 * tid;
    float2 zi = *(const float2*)(P.b_att + j);
    float2 zf = *(const float2*)(P.b_att + 512 + j);
    float2 zg = *(const float2*)(P.b_att + 1024 + j);
    float2 zo = *(const float2*)(P.b_att + 1536 + j);
    for (int cc = 4; cc <= 7; ++cc) {
      const float* q = P.zX + ((size_t)cc * NB + b) * 2048 + j;
      float2 a = ldF2(q), f2 = ldF2(q + 512), g2 = ldF2(q + 1024), o2 = ldF2(q + 1536);
      zi.x += a.x; zi.y += a.y;
      zf.x += f2.x; zf.y += f2.y;
      zg.x += g2.x; zg.y += g2.y;
      zo.x += o2.x; zo.y += o2.y;
    }
    float2 cp = z ? make_float2(0.f, 0.f)
                  : *(const float2*)(P.ac + (size_t)pp * NB * 512 + (size_t)b * 512 + j);
    float2 hp = z ? make_float2(0.f, 0.f)
                  : *(const float2*)(P.ah + (size_t)pp * NB * 512 + (size_t)b * 512 + j);
    float cnx = sigm(zf.x) * cp.x + sigm(zi.x) * tanhf(zg.x);
    float cny = sigm(zf.y) * cp.y + sigm(zi.y) * tanhf(zg.y);
    float hrx = sigm(zo.x) * tanhf(cnx);
    float hry = sigm(zo.y) * tanhf(cny);
    ah_s[j] = hrx;
    ah_s[j + 1] = hry;
    *(float2*)(P.ah + (size_t)(s & 1) * NB * 512 + (size_t)b * 512 + j) =
        make_float2(m * hrx + (1.f - m) * hp.x, m * hry + (1.f - m) * hp.y);
    *(float2*)(P.ac + (size_t)(s & 1) * NB * 512 + (size_t)b * 512 + j) =
        make_float2(m * cnx + (1.f - m) * cp.x, m * cny + (1.f - m) * cp.y);
  }
  __syncthreads();
  {
    int cc2 = tid & 31, ch = tid >> 5;
    float ssum = 0.f;
    if (cc2 < 30)
      for (int k = ch * 64; k < ch * 64 + 64; ++k) ssum += ah_s[k] * P.w_proj[k * 30 + cc2];
    red_s[ch * 32 + cc2] = ssum;
  }
  __syncthreads();
  if (tid < 30) {
    float ssum = P.b_proj[tid];
    for (int ch = 0; ch < 8; ++ch) ssum += red_s[ch * 32 + tid];
    pr_s[tid] = ssum;
  }
  __syncthreads();
  if (tid < WMc) {
    float kp = z ? 0.f : P.ak[(size_t)pp * NB * AKS + (size_t)b * AKS + tid];
    float a_t = softplusf(pr_s[tid]);
    float b_t = softplusf(pr_s[WMc + tid]);
    float k_t = kp + softplusf(pr_s[2 * WMc + tid]);
    abk[tid] = a_t;
    abk[32 + tid] = b_t;
    abk[64 + tid] = k_t;
    P.ak[(size_t)(s & 1) * NB * AKS + (size_t)b * AKS + tid] = m * k_t + (1.f - m) * kp;
  }
  __syncthreads();
  {
    int u = tid;
    float ssum = 0.f;
#pragma unroll
    for (int gg = 0; gg < WMc; ++gg) {
      float dd = abk[64 + gg] - (float)u;
      ssum += abk[gg] * expf(-abk[32 + gg] * dd * dd);
    }
    phi_s[u] = ssum * P.text_mask[u * NB + b];
  }
  __syncthreads();
  {
    int dcol = tid;
    float ssum = 0.f;
#pragma unroll 8
    for (int u = 0; u < NU; ++u)
      ssum += phi_s[u] * __builtin_nontemporal_load(P.ctx + ((size_t)u * NB + b) * 256 + dcol);
    float wprev = z ? 0.f : P.aw[(size_t)pp * NB * 256 + (size_t)b * 256 + dcol];
    P.aw[(size_t)(s & 1) * NB * 256 + (size_t)b * 256 + dcol] = m * ssum + (1.f - m) * wprev;
  }
}

// =====================================================================================
extern "C" void kernel_launch(void* const* d_in, const int* in_sizes, int n_in,
                              void* d_out, int out_size, void* d_ws, size_t ws_size,
                              hipStream_t stream) {
  const float* in_mels = (const float*)d_in[0];
  const float* mel_mask = (const float*)d_in[1];
  const int* text = (const int*)d_in[2];
  const float* text_mask = (const float*)d_in[3];
  const float* w_pre1 = (const float*)d_in[4];
  const float* b_pre1 = (const float*)d_in[5];
  const float* w_pre2 = (const float*)d_in[6];
  const float* b_pre2 = (const float*)d_in[7];
  const float* emb = (const float*)d_in[8];
  const float* conv_w0 = (const float*)d_in[9];
  const float* conv_b0 = (const float*)d_in[10];
  const float* conv_w1 = (const float*)d_in[11];
  const float* conv_b1 = (const float*)d_in[12];
  const float* conv_w2 = (const float*)d_in[13];
  const float* conv_b2 = (const float*)d_in[14];
  const float* w_bif = (const float*)d_in[15];
  const float* b_bif = (const float*)d_in[16];
  const float* w_bib = (const float*)d_in[17];
  const float* b_bib = (const float*)d_in[18];
  const float* w_att = (const float*)d_in[19];
  const float* b_att = (const float*)d_in[20];
  const float* w_proj = (const float*)d_in[21];
  const float* b_proj = (const float*)d_in[22];
  const float* w_rnn1 = (const float*)d_in[23];
  const float* b_rnn1 = (const float*)d_in[24];
  const float* w_rnn2 = (const float*)d_in[25];
  const float* b_rnn2 = (const float*)d_in[26];
  const float* w_outp = (const float*)d_in[27];
  const float* b_outp = (const float*)d_in[28];

  float* ws = (float*)d_ws;
  size_t off = 0;
  auto alloc = [&](size_t n) {
    float* p = ws + off;
    off += (n + 63) & ~(size_t)63;
    return p;
  };
  float* corr = alloc((size_t)NT * NB * PREc);
  float* embx = alloc((size_t)NB * NU * EMBc);
  float* wpkR = alloc(WSZ);  // hi+lo planes (30.4MB); also prenet tmp / conv ping
  float* zX = alloc((size_t)12 * NB * 2048);
  float* ctx = alloc((size_t)NU * NB * 2 * ENCc);  // also conv pong
  float* convbuf = alloc((size_t)NB * NU * NFc);   // final conv output (encoder input)
  float* aw = alloc((size_t)2 * NB * 2 * ENCc);
  float* ak = alloc((size_t)2 * NB * AKS);
  float* ah = alloc((size_t)2 * NB * DECc);
  float* ac = alloc((size_t)2 * NB * DECc);
  float* h1 = alloc((size_t)2 * NB * DECc);
  float* c1 = alloc((size_t)2 * NB * DECc);
  float* c2 = alloc((size_t)2 * NB * DECc);
  float* outs = alloc((size_t)NT * NB * DECc);  // h2 rows; encoder zx (fp16) overlays
  float* weff0 = alloc((size_t)5 * EMBc * NFc);
  float* beff0 = alloc(NFc);
  float* weff1 = alloc((size_t)5 * NFc * NFc);
  float* beff1 = alloc(NFc);
  float* weff2 = alloc((size_t)5 * NFc * NFc);
  float* beff2 = alloc(NFc);
  float* zerob = alloc(1024);
  float* flagsf = alloc(512);
  unsigned* flags = (unsigned*)flagsf;

  unsigned short* Wpk = (unsigned short*)wpkR;
  _Float16* zx = (_Float16*)outs;  // 2*256*64*512 halves = 33.5MB, dead before decoder writes outs
  float* tmp = wpkR;
  float* convA = wpkR;
  float* convB = ctx;

  hipMemsetAsync(zerob, 0, 1024 * sizeof(float), stream);
  hipMemsetAsync(flags, 0, 512 * sizeof(unsigned), stream);

  // ---- prenet ----
  k_dense<NMELc, PREc, 8><<<NT * NB / 8, 128, 0, stream>>>(in_mels, w_pre1, b_pre1, tmp, NT * NB);
  k_dense<PREc, PREc, 8><<<NT * NB / 8, 128, 0, stream>>>(tmp, w_pre2, b_pre2, corr, NT * NB);

  // ---- text conv stacks: embx -> convB -> convA -> convbuf ----
  k_embed<<<(NB * NU * EMBc + 255) / 256, 256, 0, stream>>>(text, emb, embx);
  k_weff<EMBc><<<(5 * EMBc * NFc + 255) / 256, 256, 0, stream>>>(conv_w0, conv_b0, weff0, beff0);
  k_weff<NFc><<<(5 * NFc * NFc + 255) / 256, 256, 0, stream>>>(conv_w1, conv_b1, weff1, beff1);
  k_weff<NFc><<<(5 * NFc * NFc + 255) / 256, 256, 0, stream>>>(conv_w2, conv_b2, weff2, beff2);
  k_conv<EMBc, false><<<dim3(NU / 8, NB), 128, 0, stream>>>(embx, weff0, beff0, convB);
  k_conv<NFc, true><<<dim3(NU / 8, NB), 128, 0, stream>>>(convB, weff1, beff1, convA);
  k_conv<NFc, true><<<dim3(NU / 8, NB), 128, 0, stream>>>(convA, weff2, beff2, convbuf);

  // ---- prepack decoder weights (frees wpkR conv use) ----
  k_wcvt<<<dim3(116, 4), 256, 0, stream>>>(w_rnn1, w_att, w_rnn2, Wpk);

  // ---- encoder: x-part precompute + persistent block-local BiLSTM ----
  k_zx<<<dim3(512, 8), 512, 0, stream>>>(w_bif, b_bif, w_bib, b_bib, convbuf, zx);
  k_encP2<<<32, 256, 0, stream>>>(w_bif, w_bib, zx, text_mask, ctx);

  // ---- decoder: ONE merged launch per pipeline slot ----
  DecMp M;
  M.corr = corr; M.Wpk = Wpk;
  M.mel_mask = mel_mask; M.text_mask = text_mask; M.ctx = ctx;
  M.b_att = b_att; M.b_rnn1 = b_rnn1; M.b_rnn2 = b_rnn2;
  M.w_proj = w_proj; M.b_proj = b_proj;
  M.aw = aw; M.ak = ak; M.ah = ah; M.ac = ac;
  M.h1 = h1; M.c1 = c1; M.c2 = c2; M.outs = outs; M.zerob = zerob;
  M.zX = zX; M.flags = flags;
  for (int i = 0; i <= NT + 1; ++i) {
    k_decM<<<576, 256, 0, stream>>>(M, i);
  }

  // ---- output projection ----
  k_dense<DECc, NMELc, 8><<<NT * NB / 8, 128, 0, stream>>>(outs, w_outp, b_outp, (float*)d_out,
                                                           NT * NB);
}